// Round 14
// baseline (437.493 us; speedup 1.0000x reference)
//
#include <hip/hip_runtime.h>
#include <hip/hip_bf16.h>
#include <math.h>

#define DM 256      // D_MODEL
#define NL 4        // N_LAYERS
#define DI 512      // D_INNER
#define DS 16       // D_STATE
#define DC 4        // D_CONV
#define DR 16       // DT_RANK
#define NC 10       // NUM_CLASSES
#define NB 8        // B
#define LL 1024     // L
#define MR (NB*LL)  // 8192 rows
#define NCHUNK 128
#define CLEN 8

typedef __attribute__((ext_vector_type(4))) float f32x4;
typedef __attribute__((ext_vector_type(8))) short short8;

extern "C" __device__ float __ocml_native_exp2_f32(float);
__device__ __forceinline__ float exp2_f(float x) { return __ocml_native_exp2_f32(x); }
#define L2E 1.442695040888963f

__device__ __forceinline__ float silu_f(float x) {
    return x * (1.0f / (1.0f + __expf(-x)));
}
__device__ __forceinline__ float bf2f(ushort v) {
    union { unsigned u; float f; } c; c.u = ((unsigned)v) << 16; return c.f;
}
__device__ __forceinline__ ushort f2bf(float f) {   // round-to-nearest-even
    union { float f; unsigned u; } c; c.f = f;
    unsigned lsb = (c.u >> 16) & 1;
    return (ushort)((c.u + 0x7fffu + lsb) >> 16);
}
__device__ __forceinline__ void g2lds16(const void* g, void* l) {
    __builtin_amdgcn_global_load_lds((const __attribute__((address_space(1))) void*)g,
                                     (__attribute__((address_space(3))) void*)l, 16, 0, 0);
}

// ---- weight fp32 -> bf16 conversion + Aval table ----
#define IPW_N (NL*2*DI*DM)   // 1048576
#define XPW_N (NL*64*DI)     // 131072 (padded)
#define OPW_N (NL*DM*DI)     // 524288
#define AV_N  (NL*DI*DS)     // 32768
__global__ __launch_bounds__(256) void convert_weights_kernel(
        const float* __restrict__ ipw, const float* __restrict__ xpw,
        const float* __restrict__ opw, const float* __restrict__ A_log,
        ushort* __restrict__ ipw_b, ushort* __restrict__ xpw_b,
        ushort* __restrict__ opw_b, float* __restrict__ Av) {
    int t = blockIdx.x * 256 + threadIdx.x;
    if (t < IPW_N) { ipw_b[t] = f2bf(ipw[t]); return; }
    t -= IPW_N;
    if (t < XPW_N) {
        int l = t >> 15, r = (t >> 9) & 63, k = t & 511;
        xpw_b[t] = (r < 48) ? f2bf(xpw[((size_t)l * 48 + r) * DI + k]) : (ushort)0;
        return;
    }
    t -= XPW_N;
    if (t < OPW_N) { opw_b[t] = f2bf(opw[t]); return; }
    t -= OPW_N;
    if (t < AV_N) Av[t] = -__expf(A_log[t]) * L2E;
}

// fused input projection + layer-0 LN: v = x[m]*iw[t]+ib[t]; hres=v; hln=LN(v)
__global__ __launch_bounds__(256) void input_ln_kernel(
        const float* __restrict__ x, const float* __restrict__ iw,
        const float* __restrict__ ib,
        const float* __restrict__ lnw, const float* __restrict__ lnb,
        float* __restrict__ hres, ushort* __restrict__ hln) {
    int row = blockIdx.x, t = threadIdx.x;
    float v = x[row] * iw[t] + ib[t];
    float s = v, q = v * v;
#pragma unroll
    for (int o = 32; o >= 1; o >>= 1) { s += __shfl_xor(s, o); q += __shfl_xor(q, o); }
    __shared__ float red[8];
    int wid = t >> 6;
    if ((t & 63) == 0) { red[wid] = s; red[4 + wid] = q; }
    __syncthreads();
    s = red[0] + red[1] + red[2] + red[3];
    q = red[4] + red[5] + red[6] + red[7];
    float mu = s * (1.0f / DM);
    float var = q * (1.0f / DM) - mu * mu;
    float rs = rsqrtf(var + 1e-5f);
    hres[row * DM + t] = v;
    hln[row * DM + t] = f2bf((v - mu) * rs * lnw[t] + lnb[t]);
}

// ---- bf16 MFMA GEMM: C[M,N] = A[M,K] @ W[N,K]^T ----
// MODE 0: bf16 out + bias; MODE 1: f32 out
template<int BM, int BN, int WM, int WN, int MODE>
__global__ __launch_bounds__(256) void mfma_gemm_kernel(
        const ushort* __restrict__ A, int lda,
        const ushort* __restrict__ W,
        const float* __restrict__ bias,
        ushort* __restrict__ Cb, float* __restrict__ Cf, int ldc, int K) {
    constexpr int FM = BM / WM / 16;
    constexpr int FN = BN / WN / 16;
    __shared__ __align__(16) char smem[(BM + BN) * 128];
    const int tid = threadIdx.x;
    const int l = tid & 63, w = tid >> 6;
    const int wr = w / WN, wc = w % WN;
    const int bm = blockIdx.x * BM, bn = blockIdx.y * BN;
    const int ldw = K;

    f32x4 acc[FM][FN] = {};

    for (int k0 = 0; k0 < K; k0 += 64) {
#pragma unroll
        for (int i = 0; i < (BM * 128 / 16) / 256; i++) {
            int lin = (i * 256 + tid) * 16;
            int q = lin ^ (((lin >> 7) & 7) << 4);
            g2lds16(A + (size_t)(bm + (q >> 7)) * lda + k0 + ((q & 127) >> 1), smem + lin);
        }
#pragma unroll
        for (int i = 0; i < (BN * 128 / 16) / 256; i++) {
            int lin = (i * 256 + tid) * 16;
            int q = lin ^ (((lin >> 7) & 7) << 4);
            g2lds16(W + (size_t)(bn + (q >> 7)) * ldw + k0 + ((q & 127) >> 1),
                    smem + BM * 128 + lin);
        }
        __syncthreads();
        const int rl = l & 15;
        const int kb0 = ((l >> 4) << 3) * 2;
#pragma unroll
        for (int kk = 0; kk < 2; kk++) {
            short8 af[FM], bfr[FN];
#pragma unroll
            for (int m = 0; m < FM; m++) {
                int off = (wr * (BM / WM) + m * 16 + rl) * 128 + kk * 64 + kb0;
                off ^= ((off >> 7) & 7) << 4;
                af[m] = *(const short8*)(smem + off);
            }
#pragma unroll
            for (int n = 0; n < FN; n++) {
                int off = (wc * (BN / WN) + n * 16 + rl) * 128 + kk * 64 + kb0;
                off ^= ((off >> 7) & 7) << 4;
                bfr[n] = *(const short8*)(smem + BM * 128 + off);
            }
#pragma unroll
            for (int m = 0; m < FM; m++)
#pragma unroll
                for (int n = 0; n < FN; n++)
                    acc[m][n] = __builtin_amdgcn_mfma_f32_16x16x32_bf16(
                        af[m], bfr[n], acc[m][n], 0, 0, 0);
        }
        __syncthreads();
    }

    const int row0 = bm + wr * (BM / WM) + ((l >> 4) << 2);
    const int col0 = bn + wc * (BN / WN) + (l & 15);
#pragma unroll
    for (int m = 0; m < FM; m++) {
#pragma unroll
        for (int n = 0; n < FN; n++) {
            int col = col0 + n * 16;
            float bv = (MODE == 1) ? 0.f : bias[col];
#pragma unroll
            for (int r = 0; r < 4; r++) {
                size_t idx = (size_t)(row0 + m * 16 + r) * ldc + col;
                float v = acc[m][n][r];
                if (MODE == 0) Cb[idx] = f2bf(v + bv);
                else Cf[idx] = v;
            }
        }
    }
}

// ---- fused out_proj GEMM + residual + LayerNorm ----
__global__ __launch_bounds__(256) void outproj_ln_kernel(
        const ushort* __restrict__ A,        // ygate [MR][512] bf16
        const ushort* __restrict__ W,        // opw_b [256][512] bf16
        const float* __restrict__ bias,      // opb [256]
        float* __restrict__ hres,            // residual stream f32 [MR][256]
        const float* __restrict__ lnw, const float* __restrict__ lnb,
        ushort* __restrict__ hln) {
    constexpr int K = DI;
    __shared__ __align__(16) char smem[(32 + 256) * 128];
    const int tid = threadIdx.x;
    const int l = tid & 63, w = tid >> 6;   // w = col-quarter
    const int bm = blockIdx.x * 32;

    f32x4 acc[2][4] = {};

    for (int k0 = 0; k0 < K; k0 += 64) {
        {   // A tile: 32 rows x 128B
            int lin = tid * 16;
            int q = lin ^ (((lin >> 7) & 7) << 4);
            g2lds16(A + (size_t)(bm + (q >> 7)) * K + k0 + ((q & 127) >> 1), smem + lin);
        }
#pragma unroll
        for (int i = 0; i < 8; i++) {   // W tile: 256 rows
            int lin = (i * 256 + tid) * 16;
            int q = lin ^ (((lin >> 7) & 7) << 4);
            g2lds16(W + (size_t)(q >> 7) * K + k0 + ((q & 127) >> 1), smem + 32 * 128 + lin);
        }
        __syncthreads();
        const int rl = l & 15;
        const int kb0 = ((l >> 4) << 3) * 2;
#pragma unroll
        for (int kk = 0; kk < 2; kk++) {
            short8 af[2], bfr[4];
#pragma unroll
            for (int m = 0; m < 2; m++) {
                int off = (m * 16 + rl) * 128 + kk * 64 + kb0;
                off ^= ((off >> 7) & 7) << 4;
                af[m] = *(const short8*)(smem + off);
            }
#pragma unroll
            for (int n = 0; n < 4; n++) {
                int off = (w * 64 + n * 16 + rl) * 128 + kk * 64 + kb0;
                off ^= ((off >> 7) & 7) << 4;
                bfr[n] = *(const short8*)(smem + 32 * 128 + off);
            }
#pragma unroll
            for (int m = 0; m < 2; m++)
#pragma unroll
                for (int n = 0; n < 4; n++)
                    acc[m][n] = __builtin_amdgcn_mfma_f32_16x16x32_bf16(
                        af[m], bfr[n], acc[m][n], 0, 0, 0);
        }
        __syncthreads();
    }

    const int r0 = (l >> 4) << 2;
    const int col0 = w * 64 + (l & 15);
    float vv[2][4][4];
    float s[2][4], q[2][4];
#pragma unroll
    for (int m = 0; m < 2; m++)
#pragma unroll
        for (int r = 0; r < 4; r++) { s[m][r] = 0.f; q[m][r] = 0.f; }
#pragma unroll
    for (int m = 0; m < 2; m++) {
#pragma unroll
        for (int n = 0; n < 4; n++) {
            int col = col0 + n * 16;
            float bv = bias[col];
#pragma unroll
            for (int r = 0; r < 4; r++) {
                int row = bm + r0 + m * 16 + r;
                float x = acc[m][n][r] + bv + hres[(size_t)row * DM + col];
                vv[m][n][r] = x;
                s[m][r] += x;
                q[m][r] += x * x;
            }
        }
    }
#pragma unroll
    for (int o = 1; o < 16; o <<= 1) {
#pragma unroll
        for (int m = 0; m < 2; m++)
#pragma unroll
            for (int r = 0; r < 4; r++) {
                s[m][r] += __shfl_xor(s[m][r], o);
                q[m][r] += __shfl_xor(q[m][r], o);
            }
    }
    float* red  = (float*)smem;            // [32][4]
    float* redq = red + 128;               // [32][4]
    if ((l & 15) == 0) {
#pragma unroll
        for (int m = 0; m < 2; m++)
#pragma unroll
            for (int r = 0; r < 4; r++) {
                int rl2 = r0 + m * 16 + r;
                red[rl2 * 4 + w] = s[m][r];
                redq[rl2 * 4 + w] = q[m][r];
            }
    }
    __syncthreads();
#pragma unroll
    for (int m = 0; m < 2; m++) {
        float mu[4], rs[4];
#pragma unroll
        for (int r = 0; r < 4; r++) {
            int rl2 = r0 + m * 16 + r;
            float ts = red[rl2 * 4] + red[rl2 * 4 + 1] + red[rl2 * 4 + 2] + red[rl2 * 4 + 3];
            float tq = redq[rl2 * 4] + redq[rl2 * 4 + 1] + redq[rl2 * 4 + 2] + redq[rl2 * 4 + 3];
            mu[r] = ts * (1.0f / DM);
            float var = tq * (1.0f / DM) - mu[r] * mu[r];
            rs[r] = rsqrtf(var + 1e-5f);
        }
#pragma unroll
        for (int n = 0; n < 4; n++) {
            int col = col0 + n * 16;
            float lw = lnw[col], lb = lnb[col];
#pragma unroll
            for (int r = 0; r < 4; r++) {
                int row = bm + r0 + m * 16 + r;
                hres[(size_t)row * DM + col] = vv[m][n][r];
                hln[(size_t)row * DM + col] = f2bf((vv[m][n][r] - mu[r]) * rs[r] * lw + lb);
            }
        }
    }
}

// depthwise causal conv (K=4) + SiLU; xz bf16 (ld 1024, cols 0..511) -> u bf16
__global__ __launch_bounds__(256) void conv_silu_kernel(const ushort* __restrict__ xz,
        const float* __restrict__ cw, const float* __restrict__ cb, ushort* __restrict__ u) {
    int t = blockIdx.x * 256 + threadIdx.x;   // MR*DI/8 threads
    int d8 = (t & 63) << 3;
    int m = t >> 6;
    int l = m & (LL - 1);
    const short8 zr = {0, 0, 0, 0, 0, 0, 0, 0};
    const size_t base = (size_t)m * 1024 + d8;
    short8 r3 = *(const short8*)(xz + base);
    short8 r2 = (l >= 1) ? *(const short8*)(xz + base - 1024) : zr;
    short8 r1 = (l >= 2) ? *(const short8*)(xz + base - 2048) : zr;
    short8 r0 = (l >= 3) ? *(const short8*)(xz + base - 3072) : zr;
    short8 o;
#pragma unroll
    for (int j = 0; j < 8; j++) {
        int d = d8 + j;
        float4 w4 = *reinterpret_cast<const float4*>(&cw[d * 4]);
        float a = cb[d] + w4.w * bf2f((ushort)r3[j]);
        a += w4.z * bf2f((ushort)r2[j]);
        a += w4.y * bf2f((ushort)r1[j]);
        a += w4.x * bf2f((ushort)r0[j]);
        o[j] = (short)f2bf(silu_f(a));
    }
    *(short8*)(u + (size_t)m * DI + d8) = o;
}

// ---- chunked parallel scan, algebraic split ----
// Phase 1: chunk-local pass. Outputs: S, sdv, packed (cumd,yloc) bf16x2.
__global__ __launch_bounds__(256, 4) void scan_phase1_kernel(
        const ushort* __restrict__ u, const float* __restrict__ x_dbl,
        const float* __restrict__ Av,
        const float* __restrict__ dtw, const float* __restrict__ dtb,
        const float* __restrict__ Dp,
        float* __restrict__ sdv, float* __restrict__ Sbuf,
        unsigned* __restrict__ cy) {
    __shared__ __align__(16) float xs[CLEN * 64];
    const int tid = threadIdx.x;
    const int bc = blockIdx.x >> 1;
    const int d = ((blockIdx.x & 1) << 8) + tid;
    const int c = bc & (NCHUNK - 1);
    const int b = bc >> 7;
    const int m0 = b * LL + c * CLEN;
    *reinterpret_cast<float2*>(&xs[tid * 2]) =
        *reinterpret_cast<const float2*>(&x_dbl[(size_t)m0 * 64 + tid * 2]);

    float Aval[DS], h[DS], wreg[DR];
#pragma unroll
    for (int q = 0; q < 4; q++) {
        float4 a4 = *reinterpret_cast<const float4*>(&Av[d * DS + q * 4]);
        Aval[q*4+0] = a4.x; Aval[q*4+1] = a4.y; Aval[q*4+2] = a4.z; Aval[q*4+3] = a4.w;
        float4 w4 = *reinterpret_cast<const float4*>(&dtw[d * DR + q * 4]);
        wreg[q*4] = w4.x; wreg[q*4+1] = w4.y; wreg[q*4+2] = w4.z; wreg[q*4+3] = w4.w;
    }
    float dbv = dtb[d];
    float Dval = Dp[d];
#pragma unroll
    for (int n = 0; n < DS; n++) h[n] = 0.f;
    const ushort* up = u + (size_t)m0 * DI + d;
    unsigned* cyp = cy + (size_t)m0 * DI + d;
    float sd = 0.f;
    __syncthreads();
    float uv = bf2f(up[0]);
#pragma unroll
    for (int t = 0; t < CLEN; t++) {
        float uvn = (t + 1 < CLEN) ? bf2f(up[(size_t)(t + 1) * DI]) : 0.f;
        const float* xr = &xs[t * 64];
        float4 x0 = *reinterpret_cast<const float4*>(xr);
        float4 x1 = *reinterpret_cast<const float4*>(xr + 4);
        float4 x2 = *reinterpret_cast<const float4*>(xr + 8);
        float4 x3 = *reinterpret_cast<const float4*>(xr + 12);
        float4 B0 = *reinterpret_cast<const float4*>(xr + 16);
        float4 B1 = *reinterpret_cast<const float4*>(xr + 20);
        float4 B2 = *reinterpret_cast<const float4*>(xr + 24);
        float4 B3 = *reinterpret_cast<const float4*>(xr + 28);
        float4 C0 = *reinterpret_cast<const float4*>(xr + 32);
        float4 C1 = *reinterpret_cast<const float4*>(xr + 36);
        float4 C2 = *reinterpret_cast<const float4*>(xr + 40);
        float4 C3 = *reinterpret_cast<const float4*>(xr + 44);
        float p0 = dbv + wreg[0]*x0.x + wreg[1]*x0.y + wreg[2]*x0.z + wreg[3]*x0.w;
        float p1 = wreg[4]*x1.x + wreg[5]*x1.y + wreg[6]*x1.z + wreg[7]*x1.w;
        float p2 = wreg[8]*x2.x + wreg[9]*x2.y + wreg[10]*x2.z + wreg[11]*x2.w;
        float p3 = wreg[12]*x3.x + wreg[13]*x3.y + wreg[14]*x3.z + wreg[15]*x3.w;
        float z = (p0 + p1) + (p2 + p3);
        float dv = (z > 20.0f) ? z : __logf(1.0f + __expf(z));
        sd += dv;
        float du = dv * uv;
        float a0, a1, a2, a3;
        h[0]  = exp2_f(dv*Aval[0])  * h[0]  + du * B0.x;  a0  = h[0]  * C0.x;
        h[1]  = exp2_f(dv*Aval[1])  * h[1]  + du * B0.y;  a0 += h[1]  * C0.y;
        h[2]  = exp2_f(dv*Aval[2])  * h[2]  + du * B0.z;  a0 += h[2]  * C0.z;
        h[3]  = exp2_f(dv*Aval[3])  * h[3]  + du * B0.w;  a0 += h[3]  * C0.w;
        h[4]  = exp2_f(dv*Aval[4])  * h[4]  + du * B1.x;  a1  = h[4]  * C1.x;
        h[5]  = exp2_f(dv*Aval[5])  * h[5]  + du * B1.y;  a1 += h[5]  * C1.y;
        h[6]  = exp2_f(dv*Aval[6])  * h[6]  + du * B1.z;  a1 += h[6]  * C1.z;
        h[7]  = exp2_f(dv*Aval[7])  * h[7]  + du * B1.w;  a1 += h[7]  * C1.w;
        h[8]  = exp2_f(dv*Aval[8])  * h[8]  + du * B2.x;  a2  = h[8]  * C2.x;
        h[9]  = exp2_f(dv*Aval[9])  * h[9]  + du * B2.y;  a2 += h[9]  * C2.y;
        h[10] = exp2_f(dv*Aval[10]) * h[10] + du * B2.z;  a2 += h[10] * C2.z;
        h[11] = exp2_f(dv*Aval[11]) * h[11] + du * B2.w;  a2 += h[11] * C2.w;
        h[12] = exp2_f(dv*Aval[12]) * h[12] + du * B3.x;  a3  = h[12] * C3.x;
        h[13] = exp2_f(dv*Aval[13]) * h[13] + du * B3.y;  a3 += h[13] * C3.y;
        h[14] = exp2_f(dv*Aval[14]) * h[14] + du * B3.z;  a3 += h[14] * C3.z;
        h[15] = exp2_f(dv*Aval[15]) * h[15] + du * B3.w;  a3 += h[15] * C3.w;
        float yv = ((a0 + a1) + (a2 + a3)) + Dval * uv;
        cyp[(size_t)t * DI] = (unsigned)f2bf(sd) | ((unsigned)f2bf(yv) << 16);
        uv = uvn;
    }
    size_t base = ((size_t)((b * NCHUNK + c) * DI + d)) * DS;
#pragma unroll
    for (int q = 0; q < 4; q++)
        *reinterpret_cast<float4*>(&Sbuf[base + q * 4]) =
            make_float4(h[q*4], h[q*4+1], h[q*4+2], h[q*4+3]);
    sdv[(b * NCHUNK + c) * DI + d] = sd;
}

// Phase 2: per (b,d,n) thread; batch-8 deep prefetch pipeline over 128 chunks.
__global__ __launch_bounds__(256) void scan_phase2_kernel(
        const float* __restrict__ sdv, const float* __restrict__ Av,
        float* __restrict__ Sbuf) {
    int gid = blockIdx.x * 256 + threadIdx.x;
    int dn = gid & (DI * DS - 1);
    int b = gid >> 13;
    int n = dn & 15, d = dn >> 4;
    float Aval = Av[d * DS + n];
    size_t idx0 = (size_t)b * NCHUNK * DI * DS + dn;
    const size_t stride = (size_t)DI * DS;
    int sb0 = b * NCHUNK * DI + d;
    float h = 0.f;
    float S0[8], sd0[8];
#pragma unroll
    for (int j = 0; j < 8; j++) {
        S0[j] = Sbuf[idx0 + (size_t)j * stride];
        sd0[j] = sdv[sb0 + j * DI];
    }
    for (int g = 0; g < NCHUNK / 8; g++) {
        float S1[8], sd1[8];
        if (g < NCHUNK / 8 - 1) {
            int c1 = g * 8 + 8;
#pragma unroll
            for (int j = 0; j < 8; j++) {
                S1[j] = Sbuf[idx0 + (size_t)(c1 + j) * stride];
                sd1[j] = sdv[sb0 + (c1 + j) * DI];
            }
        } else {
#pragma unroll
            for (int j = 0; j < 8; j++) { S1[j] = 0.f; sd1[j] = 0.f; }
        }
#pragma unroll
        for (int j = 0; j < 8; j++) {
            float P = exp2_f(Aval * sd0[j]);
            Sbuf[idx0 + (size_t)(g * 8 + j) * stride] = h;
            h = P * h + S0[j];
        }
#pragma unroll
        for (int j = 0; j < 8; j++) { S0[j] = S1[j]; sd0[j] = sd1[j]; }
    }
}

// Phase 3 lite: y = (yloc + sum_n C[n]*exp2(Aval[n]*cumd)*hinit[n]) * silu(res)
__global__ __launch_bounds__(256, 4) void scan_phase3_kernel(
        const unsigned* __restrict__ cy,
        const float* __restrict__ x_dbl, const float* __restrict__ Av,
        const float* __restrict__ Sbuf,
        const ushort* __restrict__ xz, ushort* __restrict__ y) {
    __shared__ __align__(16) float cs[CLEN * 16];   // C slab only
    const int tid = threadIdx.x;
    const int bc = blockIdx.x >> 1;
    const int d = ((blockIdx.x & 1) << 8) + tid;
    const int c = bc & (NCHUNK - 1);
    const int b = bc >> 7;
    const int m0 = b * LL + c * CLEN;
    if (tid < CLEN * 16) {   // stage C columns (32..47) of chunk rows
        int tt = tid >> 4, k = tid & 15;
        cs[tid] = x_dbl[(size_t)(m0 + tt) * 64 + 32 + k];
    }
    float Aval[DS], hi[DS];
    size_t base = ((size_t)((b * NCHUNK + c) * DI + d)) * DS;
#pragma unroll
    for (int q = 0; q < 4; q++) {
        float4 a4 = *reinterpret_cast<const float4*>(&Av[d * DS + q * 4]);
        Aval[q*4+0] = a4.x; Aval[q*4+1] = a4.y; Aval[q*4+2] = a4.z; Aval[q*4+3] = a4.w;
        float4 h4 = *reinterpret_cast<const float4*>(&Sbuf[base + q * 4]);
        hi[q*4] = h4.x; hi[q*4+1] = h4.y; hi[q*4+2] = h4.z; hi[q*4+3] = h4.w;
    }
    const unsigned* cyp = cy + (size_t)m0 * DI + d;
    const ushort* rp = xz + (size_t)m0 * 1024 + 512 + d;
    ushort* yp = y + (size_t)m0 * DI + d;
    __syncthreads();
    unsigned cyw = cyp[0];
    float rv = bf2f(rp[0]);
#pragma unroll
    for (int t = 0; t < CLEN; t++) {
        unsigned cywn = 0; float rvn = 0.f;
        if (t + 1 < CLEN) {
            cywn = cyp[(size_t)(t + 1) * DI];
            rvn = bf2f(rp[(size_t)(t + 1) * 1024]);
        }
        float cd = bf2f((ushort)(cyw & 0xffffu));
        float yl = bf2f((ushort)(cyw >> 16));
        const float* cr = &cs[t * 16];
        float4 C0 = *reinterpret_cast<const float4*>(cr);
        float4 C1 = *reinterpret_cast<const float4*>(cr + 4);
        float4 C2 = *reinterpret_cast<const float4*>(cr + 8);
        float4 C3 = *reinterpret_cast<const float4*>(cr + 12);
        float a0, a1, a2, a3;
        a0  = exp2_f(Aval[0]  * cd) * hi[0]  * C0.x;
        a0 += exp2_f(Aval[1]  * cd) * hi[1]  * C0.y;
        a0 += exp2_f(Aval[2]  * cd) * hi[2]  * C0.z;
        a0 += exp2_f(Aval[3]  * cd) * hi[3]  * C0.w;
        a1  = exp2_f(Aval[4]  * cd) * hi[4]  * C1.x;
        a1 += exp2_f(Aval[5]  * cd) * hi[5]  * C1.y;
        a1 += exp2_f(Aval[6]  * cd) * hi[6]  * C1.z;
        a1 += exp2_f(Aval[7]  * cd) * hi[7]  * C1.w;
        a2  = exp2_f(Aval[8]  * cd) * hi[8]  * C2.x;
        a2 += exp2_f(Aval[9]  * cd) * hi[9]  * C2.y;
        a2 += exp2_f(Aval[10] * cd) * hi[10] * C2.z;
        a2 += exp2_f(Aval[11] * cd) * hi[11] * C2.w;
        a3  = exp2_f(Aval[12] * cd) * hi[12] * C3.x;
        a3 += exp2_f(Aval[13] * cd) * hi[13] * C3.y;
        a3 += exp2_f(Aval[14] * cd) * hi[14] * C3.z;
        a3 += exp2_f(Aval[15] * cd) * hi[15] * C3.w;
        float yv = yl + ((a0 + a1) + (a2 + a3));
        yp[(size_t)t * DI] = f2bf(yv * silu_f(rv));
        cyw = cywn; rv = rvn;
    }
}

// pool stage 1: partial[(b*8+slice)][dm] = sum over 128 l's
__global__ __launch_bounds__(256) void pool_partial_kernel(const ushort* __restrict__ ln,
                                                           float* __restrict__ partial) {
    int bs = blockIdx.x;            // 0..63
    int b = bs >> 3, sl = bs & 7;
    int t = threadIdx.x;            // dm
    int l0 = sl * 128;
    float s = 0.f;
    for (int l = 0; l < 128; l++) s += bf2f(ln[(size_t)(b * LL + l0 + l) * DM + t]);
    partial[(bs << 8) + t] = s;
}

__global__ void cls_kernel(const float* __restrict__ partial, const float* __restrict__ cw,
                           const float* __restrict__ cb, float* __restrict__ out) {
    int t = threadIdx.x;
    if (t >= NB * NC) return;
    int b = t / NC, c = t % NC;
    float s = 0.f;
    for (int k = 0; k < DM; k++) {
        float p = 0.f;
#pragma unroll
        for (int sl = 0; sl < 8; sl++) p += partial[((b * 8 + sl) << 8) + k];
        s += p * cw[c * DM + k];
    }
    out[t] = cb[c] + s * (1.0f / LL);
}

extern "C" void kernel_launch(void* const* d_in, const int* in_sizes, int n_in,
                              void* d_out, int out_size, void* d_ws, size_t ws_size,
                              hipStream_t stream) {
    const float* x       = (const float*)d_in[0];
    const float* input_w = (const float*)d_in[1];
    const float* input_b = (const float*)d_in[2];
    const float* ln_w    = (const float*)d_in[3];
    const float* ln_b    = (const float*)d_in[4];
    const float* ipw     = (const float*)d_in[5];
    const float* ipb     = (const float*)d_in[6];
    const float* cw      = (const float*)d_in[7];
    const float* cb      = (const float*)d_in[8];
    const float* xpw     = (const float*)d_in[9];
    const float* dtw     = (const float*)d_in[10];
    const float* dtb     = (const float*)d_in[11];
    const float* A_log   = (const float*)d_in[12];
    const float* Dp      = (const float*)d_in[13];
    const float* opw     = (const float*)d_in[14];
    const float* opb     = (const float*)d_in[15];
    const float* norm_w  = (const float*)d_in[16];
    const float* norm_b  = (const float*)d_in[17];
    const float* cls_w   = (const float*)d_in[18];
    const float* cls_b   = (const float*)d_in[19];
    float* out = (float*)d_out;
    float* ws = (float*)d_ws;

    float*    hres   = ws;                                   // MR*DM f32
    ushort*   xz     = (ushort*)(hres + (size_t)MR * DM);    // MR*1024 bf16
    ushort*   ub     = xz + (size_t)MR * 1024;               // MR*DI bf16
    float*    x_dbl  = (float*)(ub + (size_t)MR * DI);       // MR*64 f32
    float*    sdvb   = x_dbl + (size_t)MR * 64;              // NB*NCHUNK*DI f32
    float*    Sbuf   = sdvb + (size_t)NB * NCHUNK * DI;      // NB*NCHUNK*DI*DS f32
    float*    partial= Sbuf + (size_t)NB * NCHUNK * DI * DS; // 64*256 f32
    ushort*   ygate  = (ushort*)(partial + 64 * 256);        // MR*DI bf16
    ushort*   hln    = ygate + (size_t)MR * DI;              // MR*DM bf16
    ushort*   ipw_b  = hln + (size_t)MR * DM;                // IPW_N
    ushort*   xpw_b  = ipw_b + IPW_N;                        // XPW_N
    ushort*   opw_b  = xpw_b + XPW_N;                        // OPW_N
    float*    Avbuf  = (float*)(opw_b + OPW_N);              // AV_N f32
    unsigned* cy     = (unsigned*)(Avbuf + AV_N);            // MR*DI packed bf16x2

    convert_weights_kernel<<<(IPW_N + XPW_N + OPW_N + AV_N) / 256, 256, 0, stream>>>(
        ipw, xpw, opw, A_log, ipw_b, xpw_b, opw_b, Avbuf);
    input_ln_kernel<<<MR, 256, 0, stream>>>(x, input_w, input_b, ln_w, ln_b, hres, hln);

    for (int i = 0; i < NL; i++) {
        mfma_gemm_kernel<128, 128, 2, 2, 0><<<dim3(MR / 128, 1024 / 128), 256, 0, stream>>>(
            hln, DM, ipw_b + (size_t)i * 2 * DI * DM, ipb + (size_t)i * 2 * DI,
            xz, nullptr, 1024, DM);
        conv_silu_kernel<<<MR * DI / 8 / 256, 256, 0, stream>>>(xz, cw + i * DI * DC, cb + i * DI, ub);
        mfma_gemm_kernel<64, 64, 4, 1, 1><<<dim3(MR / 64, 1), 256, 0, stream>>>(
            ub, DI, xpw_b + (size_t)i * 64 * DI, nullptr, nullptr, x_dbl, 64, DI);
        scan_phase1_kernel<<<NB * NCHUNK * 2, 256, 0, stream>>>(
            ub, x_dbl, Avbuf + (size_t)i * DI * DS, dtw + i * DI * DR, dtb + i * DI,
            Dp + i * DI, sdvb, Sbuf, cy);
        scan_phase2_kernel<<<NB * DI * DS / 256, 256, 0, stream>>>(
            sdvb, Avbuf + (size_t)i * DI * DS, Sbuf);
        scan_phase3_kernel<<<NB * NCHUNK * 2, 256, 0, stream>>>(
            cy, x_dbl, Avbuf + (size_t)i * DI * DS, Sbuf, xz, ygate);
        const float* nlw = (i < NL - 1) ? (ln_w + (i + 1) * DM) : norm_w;
        const float* nlb = (i < NL - 1) ? (ln_b + (i + 1) * DM) : norm_b;
        outproj_ln_kernel<<<MR / 32, 256, 0, stream>>>(
            ygate, opw_b + (size_t)i * DM * DI, opb + (size_t)i * DM,
            hres, nlw, nlb, hln);
    }

    pool_partial_kernel<<<64, 256, 0, stream>>>(hln, partial);
    cls_kernel<<<1, 128, 0, stream>>>(partial, cls_w, cls_b, out);
}

// Round 15
// 415.186 us; speedup vs baseline: 1.0537x; 1.0537x over previous
//
#include <hip/hip_runtime.h>
#include <hip/hip_bf16.h>
#include <math.h>

#define DM 256      // D_MODEL
#define NL 4        // N_LAYERS
#define DI 512      // D_INNER
#define DS 16       // D_STATE
#define DC 4        // D_CONV
#define DR 16       // DT_RANK
#define NC 10       // NUM_CLASSES
#define NB 8        // B
#define LL 1024     // L
#define MR (NB*LL)  // 8192 rows
#define NCHUNK 64
#define CLEN 16

typedef __attribute__((ext_vector_type(4))) float f32x4;
typedef __attribute__((ext_vector_type(8))) short short8;

extern "C" __device__ float __ocml_native_exp2_f32(float);
__device__ __forceinline__ float exp2_f(float x) { return __ocml_native_exp2_f32(x); }
#define L2E 1.442695040888963f

__device__ __forceinline__ float silu_f(float x) {
    return x * (1.0f / (1.0f + __expf(-x)));
}
__device__ __forceinline__ float bf2f(ushort v) {
    union { unsigned u; float f; } c; c.u = ((unsigned)v) << 16; return c.f;
}
__device__ __forceinline__ ushort f2bf(float f) {   // round-to-nearest-even
    union { float f; unsigned u; } c; c.f = f;
    unsigned lsb = (c.u >> 16) & 1;
    return (ushort)((c.u + 0x7fffu + lsb) >> 16);
}
__device__ __forceinline__ void g2lds16(const void* g, void* l) {
    __builtin_amdgcn_global_load_lds((const __attribute__((address_space(1))) void*)g,
                                     (__attribute__((address_space(3))) void*)l, 16, 0, 0);
}

// ---- weight fp32 -> bf16 conversion + Aval table ----
#define IPW_N (NL*2*DI*DM)   // 1048576
#define XPW_N (NL*64*DI)     // 131072 (padded)
#define OPW_N (NL*DM*DI)     // 524288
#define AV_N  (NL*DI*DS)     // 32768
__global__ __launch_bounds__(256) void convert_weights_kernel(
        const float* __restrict__ ipw, const float* __restrict__ xpw,
        const float* __restrict__ opw, const float* __restrict__ A_log,
        ushort* __restrict__ ipw_b, ushort* __restrict__ xpw_b,
        ushort* __restrict__ opw_b, float* __restrict__ Av) {
    int t = blockIdx.x * 256 + threadIdx.x;
    if (t < IPW_N) { ipw_b[t] = f2bf(ipw[t]); return; }
    t -= IPW_N;
    if (t < XPW_N) {
        int l = t >> 15, r = (t >> 9) & 63, k = t & 511;
        xpw_b[t] = (r < 48) ? f2bf(xpw[((size_t)l * 48 + r) * DI + k]) : (ushort)0;
        return;
    }
    t -= XPW_N;
    if (t < OPW_N) { opw_b[t] = f2bf(opw[t]); return; }
    t -= OPW_N;
    if (t < AV_N) Av[t] = -__expf(A_log[t]) * L2E;
}

// fused input projection + layer-0 LN: v = x[m]*iw[t]+ib[t]; hres=v; hln=LN(v)
__global__ __launch_bounds__(256) void input_ln_kernel(
        const float* __restrict__ x, const float* __restrict__ iw,
        const float* __restrict__ ib,
        const float* __restrict__ lnw, const float* __restrict__ lnb,
        float* __restrict__ hres, ushort* __restrict__ hln) {
    int row = blockIdx.x, t = threadIdx.x;
    float v = x[row] * iw[t] + ib[t];
    float s = v, q = v * v;
#pragma unroll
    for (int o = 32; o >= 1; o >>= 1) { s += __shfl_xor(s, o); q += __shfl_xor(q, o); }
    __shared__ float red[8];
    int wid = t >> 6;
    if ((t & 63) == 0) { red[wid] = s; red[4 + wid] = q; }
    __syncthreads();
    s = red[0] + red[1] + red[2] + red[3];
    q = red[4] + red[5] + red[6] + red[7];
    float mu = s * (1.0f / DM);
    float var = q * (1.0f / DM) - mu * mu;
    float rs = rsqrtf(var + 1e-5f);
    hres[row * DM + t] = v;
    hln[row * DM + t] = f2bf((v - mu) * rs * lnw[t] + lnb[t]);
}

// ---- bf16 MFMA GEMM: C[M,N] = A[M,K] @ W[N,K]^T ----
// MODE 0: bf16 out + bias; MODE 1: f32 out
template<int BM, int BN, int WM, int WN, int MODE>
__global__ __launch_bounds__(256) void mfma_gemm_kernel(
        const ushort* __restrict__ A, int lda,
        const ushort* __restrict__ W,
        const float* __restrict__ bias,
        ushort* __restrict__ Cb, float* __restrict__ Cf, int ldc, int K) {
    constexpr int FM = BM / WM / 16;
    constexpr int FN = BN / WN / 16;
    __shared__ __align__(16) char smem[(BM + BN) * 128];
    const int tid = threadIdx.x;
    const int l = tid & 63, w = tid >> 6;
    const int wr = w / WN, wc = w % WN;
    const int bm = blockIdx.x * BM, bn = blockIdx.y * BN;
    const int ldw = K;

    f32x4 acc[FM][FN] = {};

    for (int k0 = 0; k0 < K; k0 += 64) {
#pragma unroll
        for (int i = 0; i < (BM * 128 / 16) / 256; i++) {
            int lin = (i * 256 + tid) * 16;
            int q = lin ^ (((lin >> 7) & 7) << 4);
            g2lds16(A + (size_t)(bm + (q >> 7)) * lda + k0 + ((q & 127) >> 1), smem + lin);
        }
#pragma unroll
        for (int i = 0; i < (BN * 128 / 16) / 256; i++) {
            int lin = (i * 256 + tid) * 16;
            int q = lin ^ (((lin >> 7) & 7) << 4);
            g2lds16(W + (size_t)(bn + (q >> 7)) * ldw + k0 + ((q & 127) >> 1),
                    smem + BM * 128 + lin);
        }
        __syncthreads();
        const int rl = l & 15;
        const int kb0 = ((l >> 4) << 3) * 2;
#pragma unroll
        for (int kk = 0; kk < 2; kk++) {
            short8 af[FM], bfr[FN];
#pragma unroll
            for (int m = 0; m < FM; m++) {
                int off = (wr * (BM / WM) + m * 16 + rl) * 128 + kk * 64 + kb0;
                off ^= ((off >> 7) & 7) << 4;
                af[m] = *(const short8*)(smem + off);
            }
#pragma unroll
            for (int n = 0; n < FN; n++) {
                int off = (wc * (BN / WN) + n * 16 + rl) * 128 + kk * 64 + kb0;
                off ^= ((off >> 7) & 7) << 4;
                bfr[n] = *(const short8*)(smem + BM * 128 + off);
            }
#pragma unroll
            for (int m = 0; m < FM; m++)
#pragma unroll
                for (int n = 0; n < FN; n++)
                    acc[m][n] = __builtin_amdgcn_mfma_f32_16x16x32_bf16(
                        af[m], bfr[n], acc[m][n], 0, 0, 0);
        }
        __syncthreads();
    }

    const int row0 = bm + wr * (BM / WM) + ((l >> 4) << 2);
    const int col0 = bn + wc * (BN / WN) + (l & 15);
#pragma unroll
    for (int m = 0; m < FM; m++) {
#pragma unroll
        for (int n = 0; n < FN; n++) {
            int col = col0 + n * 16;
            float bv = (MODE == 1) ? 0.f : bias[col];
#pragma unroll
            for (int r = 0; r < 4; r++) {
                size_t idx = (size_t)(row0 + m * 16 + r) * ldc + col;
                float v = acc[m][n][r];
                if (MODE == 0) Cb[idx] = f2bf(v + bv);
                else Cf[idx] = v;
            }
        }
    }
}

// ---- fused out_proj GEMM + residual + LayerNorm (BM=16, grid 512) ----
__global__ __launch_bounds__(256) void outproj_ln_kernel(
        const ushort* __restrict__ A,        // ygate [MR][512] bf16
        const ushort* __restrict__ W,        // opw_b [256][512] bf16
        const float* __restrict__ bias,      // opb [256]
        float* __restrict__ hres,            // residual stream f32 [MR][256]
        const float* __restrict__ lnw, const float* __restrict__ lnb,
        ushort* __restrict__ hln) {
    constexpr int K = DI;
    __shared__ __align__(16) char smem[(16 + 256) * 128];
    const int tid = threadIdx.x;
    const int l = tid & 63, w = tid >> 6;   // w = col-quarter
    const int bm = blockIdx.x * 16;

    f32x4 acc[4] = {};

    for (int k0 = 0; k0 < K; k0 += 64) {
        if (tid < 128) {   // A tile: 16 rows x 128B
            int lin = tid * 16;
            int q = lin ^ (((lin >> 7) & 7) << 4);
            g2lds16(A + (size_t)(bm + (q >> 7)) * K + k0 + ((q & 127) >> 1), smem + lin);
        }
#pragma unroll
        for (int i = 0; i < 8; i++) {   // W tile: 256 rows
            int lin = (i * 256 + tid) * 16;
            int q = lin ^ (((lin >> 7) & 7) << 4);
            g2lds16(W + (size_t)(q >> 7) * K + k0 + ((q & 127) >> 1), smem + 16 * 128 + lin);
        }
        __syncthreads();
        const int rl = l & 15;
        const int kb0 = ((l >> 4) << 3) * 2;
#pragma unroll
        for (int kk = 0; kk < 2; kk++) {
            short8 af;
            {
                int off = rl * 128 + kk * 64 + kb0;
                off ^= ((off >> 7) & 7) << 4;
                af = *(const short8*)(smem + off);
            }
            short8 bfr[4];
#pragma unroll
            for (int n = 0; n < 4; n++) {
                int off = (w * 64 + n * 16 + rl) * 128 + kk * 64 + kb0;
                off ^= ((off >> 7) & 7) << 4;
                bfr[n] = *(const short8*)(smem + 16 * 128 + off);
            }
#pragma unroll
            for (int n = 0; n < 4; n++)
                acc[n] = __builtin_amdgcn_mfma_f32_16x16x32_bf16(af, bfr[n], acc[n], 0, 0, 0);
        }
        __syncthreads();
    }

    const int r0 = (l >> 4) << 2;          // 0,4,8,12
    const int col0 = w * 64 + (l & 15);
    float vv[4][4];
    float s[4], q[4];
#pragma unroll
    for (int r = 0; r < 4; r++) { s[r] = 0.f; q[r] = 0.f; }
#pragma unroll
    for (int n = 0; n < 4; n++) {
        int col = col0 + n * 16;
        float bv = bias[col];
#pragma unroll
        for (int r = 0; r < 4; r++) {
            int row = bm + r0 + r;
            float x = acc[n][r] + bv + hres[(size_t)row * DM + col];
            vv[n][r] = x;
            s[r] += x;
            q[r] += x * x;
        }
    }
#pragma unroll
    for (int o = 1; o < 16; o <<= 1) {
#pragma unroll
        for (int r = 0; r < 4; r++) {
            s[r] += __shfl_xor(s[r], o);
            q[r] += __shfl_xor(q[r], o);
        }
    }
    float* red  = (float*)smem;            // [16][4]
    float* redq = red + 64;                // [16][4]
    if ((l & 15) == 0) {
#pragma unroll
        for (int r = 0; r < 4; r++) {
            int rl2 = r0 + r;
            red[rl2 * 4 + w] = s[r];
            redq[rl2 * 4 + w] = q[r];
        }
    }
    __syncthreads();
    float mu[4], rs[4];
#pragma unroll
    for (int r = 0; r < 4; r++) {
        int rl2 = r0 + r;
        float ts = red[rl2 * 4] + red[rl2 * 4 + 1] + red[rl2 * 4 + 2] + red[rl2 * 4 + 3];
        float tq = redq[rl2 * 4] + redq[rl2 * 4 + 1] + redq[rl2 * 4 + 2] + redq[rl2 * 4 + 3];
        mu[r] = ts * (1.0f / DM);
        float var = tq * (1.0f / DM) - mu[r] * mu[r];
        rs[r] = rsqrtf(var + 1e-5f);
    }
#pragma unroll
    for (int n = 0; n < 4; n++) {
        int col = col0 + n * 16;
        float lw = lnw[col], lb = lnb[col];
#pragma unroll
        for (int r = 0; r < 4; r++) {
            int row = bm + r0 + r;
            hres[(size_t)row * DM + col] = vv[n][r];
            hln[(size_t)row * DM + col] = f2bf((vv[n][r] - mu[r]) * rs[r] * lw + lb);
        }
    }
}

// depthwise causal conv (K=4) + SiLU; xz bf16 (ld 1024, cols 0..511) -> u bf16
__global__ __launch_bounds__(256) void conv_silu_kernel(const ushort* __restrict__ xz,
        const float* __restrict__ cw, const float* __restrict__ cb, ushort* __restrict__ u) {
    int t = blockIdx.x * 256 + threadIdx.x;   // MR*DI/8 threads
    int d8 = (t & 63) << 3;
    int m = t >> 6;
    int l = m & (LL - 1);
    const short8 zr = {0, 0, 0, 0, 0, 0, 0, 0};
    const size_t base = (size_t)m * 1024 + d8;
    short8 r3 = *(const short8*)(xz + base);
    short8 r2 = (l >= 1) ? *(const short8*)(xz + base - 1024) : zr;
    short8 r1 = (l >= 2) ? *(const short8*)(xz + base - 2048) : zr;
    short8 r0 = (l >= 3) ? *(const short8*)(xz + base - 3072) : zr;
    short8 o;
#pragma unroll
    for (int j = 0; j < 8; j++) {
        int d = d8 + j;
        float4 w4 = *reinterpret_cast<const float4*>(&cw[d * 4]);
        float a = cb[d] + w4.w * bf2f((ushort)r3[j]);
        a += w4.z * bf2f((ushort)r2[j]);
        a += w4.y * bf2f((ushort)r1[j]);
        a += w4.x * bf2f((ushort)r0[j]);
        o[j] = (short)f2bf(silu_f(a));
    }
    *(short8*)(u + (size_t)m * DI + d8) = o;
}

// ---- chunked parallel scan, algebraic split ----
// Phase 1: chunk-local pass. Outputs: S, sdv, packed (cumd,yloc) bf16x2.
__global__ __launch_bounds__(256, 4) void scan_phase1_kernel(
        const ushort* __restrict__ u, const float* __restrict__ x_dbl,
        const float* __restrict__ Av,
        const float* __restrict__ dtw, const float* __restrict__ dtb,
        const float* __restrict__ Dp,
        float* __restrict__ sdv, float* __restrict__ Sbuf,
        unsigned* __restrict__ cy) {
    __shared__ __align__(16) float xs[CLEN * 64];
    const int tid = threadIdx.x;
    const int bc = blockIdx.x >> 1;
    const int d = ((blockIdx.x & 1) << 8) + tid;
    const int c = bc & (NCHUNK - 1);
    const int b = bc >> 6;
    const int m0 = b * LL + c * CLEN;
    *reinterpret_cast<float4*>(&xs[tid * 4]) =
        *reinterpret_cast<const float4*>(&x_dbl[(size_t)m0 * 64 + tid * 4]);

    float Aval[DS], h[DS], wreg[DR];
#pragma unroll
    for (int q = 0; q < 4; q++) {
        float4 a4 = *reinterpret_cast<const float4*>(&Av[d * DS + q * 4]);
        Aval[q*4+0] = a4.x; Aval[q*4+1] = a4.y; Aval[q*4+2] = a4.z; Aval[q*4+3] = a4.w;
        float4 w4 = *reinterpret_cast<const float4*>(&dtw[d * DR + q * 4]);
        wreg[q*4] = w4.x; wreg[q*4+1] = w4.y; wreg[q*4+2] = w4.z; wreg[q*4+3] = w4.w;
    }
    float dbv = dtb[d];
    float Dval = Dp[d];
#pragma unroll
    for (int n = 0; n < DS; n++) h[n] = 0.f;
    const ushort* up = u + (size_t)m0 * DI + d;
    unsigned* cyp = cy + (size_t)m0 * DI + d;
    float sd = 0.f;
    __syncthreads();
    float uv = bf2f(up[0]);
    for (int t = 0; t < CLEN; t++) {
        float uvn = (t + 1 < CLEN) ? bf2f(up[(size_t)(t + 1) * DI]) : 0.f;
        const float* xr = &xs[t * 64];
        float4 x0 = *reinterpret_cast<const float4*>(xr);
        float4 x1 = *reinterpret_cast<const float4*>(xr + 4);
        float4 x2 = *reinterpret_cast<const float4*>(xr + 8);
        float4 x3 = *reinterpret_cast<const float4*>(xr + 12);
        float4 B0 = *reinterpret_cast<const float4*>(xr + 16);
        float4 B1 = *reinterpret_cast<const float4*>(xr + 20);
        float4 B2 = *reinterpret_cast<const float4*>(xr + 24);
        float4 B3 = *reinterpret_cast<const float4*>(xr + 28);
        float4 C0 = *reinterpret_cast<const float4*>(xr + 32);
        float4 C1 = *reinterpret_cast<const float4*>(xr + 36);
        float4 C2 = *reinterpret_cast<const float4*>(xr + 40);
        float4 C3 = *reinterpret_cast<const float4*>(xr + 44);
        float p0 = dbv + wreg[0]*x0.x + wreg[1]*x0.y + wreg[2]*x0.z + wreg[3]*x0.w;
        float p1 = wreg[4]*x1.x + wreg[5]*x1.y + wreg[6]*x1.z + wreg[7]*x1.w;
        float p2 = wreg[8]*x2.x + wreg[9]*x2.y + wreg[10]*x2.z + wreg[11]*x2.w;
        float p3 = wreg[12]*x3.x + wreg[13]*x3.y + wreg[14]*x3.z + wreg[15]*x3.w;
        float z = (p0 + p1) + (p2 + p3);
        float dv = (z > 20.0f) ? z : __logf(1.0f + __expf(z));
        sd += dv;
        float du = dv * uv;
        float a0, a1, a2, a3;
        h[0]  = exp2_f(dv*Aval[0])  * h[0]  + du * B0.x;  a0  = h[0]  * C0.x;
        h[1]  = exp2_f(dv*Aval[1])  * h[1]  + du * B0.y;  a0 += h[1]  * C0.y;
        h[2]  = exp2_f(dv*Aval[2])  * h[2]  + du * B0.z;  a0 += h[2]  * C0.z;
        h[3]  = exp2_f(dv*Aval[3])  * h[3]  + du * B0.w;  a0 += h[3]  * C0.w;
        h[4]  = exp2_f(dv*Aval[4])  * h[4]  + du * B1.x;  a1  = h[4]  * C1.x;
        h[5]  = exp2_f(dv*Aval[5])  * h[5]  + du * B1.y;  a1 += h[5]  * C1.y;
        h[6]  = exp2_f(dv*Aval[6])  * h[6]  + du * B1.z;  a1 += h[6]  * C1.z;
        h[7]  = exp2_f(dv*Aval[7])  * h[7]  + du * B1.w;  a1 += h[7]  * C1.w;
        h[8]  = exp2_f(dv*Aval[8])  * h[8]  + du * B2.x;  a2  = h[8]  * C2.x;
        h[9]  = exp2_f(dv*Aval[9])  * h[9]  + du * B2.y;  a2 += h[9]  * C2.y;
        h[10] = exp2_f(dv*Aval[10]) * h[10] + du * B2.z;  a2 += h[10] * C2.z;
        h[11] = exp2_f(dv*Aval[11]) * h[11] + du * B2.w;  a2 += h[11] * C2.w;
        h[12] = exp2_f(dv*Aval[12]) * h[12] + du * B3.x;  a3  = h[12] * C3.x;
        h[13] = exp2_f(dv*Aval[13]) * h[13] + du * B3.y;  a3 += h[13] * C3.y;
        h[14] = exp2_f(dv*Aval[14]) * h[14] + du * B3.z;  a3 += h[14] * C3.z;
        h[15] = exp2_f(dv*Aval[15]) * h[15] + du * B3.w;  a3 += h[15] * C3.w;
        float yv = ((a0 + a1) + (a2 + a3)) + Dval * uv;
        cyp[(size_t)t * DI] = (unsigned)f2bf(sd) | ((unsigned)f2bf(yv) << 16);
        uv = uvn;
    }
    size_t base = ((size_t)((b * NCHUNK + c) * DI + d)) * DS;
#pragma unroll
    for (int q = 0; q < 4; q++)
        *reinterpret_cast<float4*>(&Sbuf[base + q * 4]) =
            make_float4(h[q*4], h[q*4+1], h[q*4+2], h[q*4+3]);
    sdv[(b * NCHUNK + c) * DI + d] = sd;
}

// Phase 2: per (b,d,n) thread; batch-8 deep prefetch pipeline.
__global__ __launch_bounds__(256) void scan_phase2_kernel(
        const float* __restrict__ sdv, const float* __restrict__ Av,
        float* __restrict__ Sbuf) {
    int gid = blockIdx.x * 256 + threadIdx.x;
    int dn = gid & (DI * DS - 1);
    int b = gid >> 13;
    int n = dn & 15, d = dn >> 4;
    float Aval = Av[d * DS + n];
    size_t idx0 = (size_t)b * NCHUNK * DI * DS + dn;
    const size_t stride = (size_t)DI * DS;
    int sb0 = b * NCHUNK * DI + d;
    float h = 0.f;
    float S0[8], sd0[8];
#pragma unroll
    for (int j = 0; j < 8; j++) {
        S0[j] = Sbuf[idx0 + (size_t)j * stride];
        sd0[j] = sdv[sb0 + j * DI];
    }
    for (int g = 0; g < NCHUNK / 8; g++) {
        float S1[8], sd1[8];
        if (g < NCHUNK / 8 - 1) {
            int c1 = g * 8 + 8;
#pragma unroll
            for (int j = 0; j < 8; j++) {
                S1[j] = Sbuf[idx0 + (size_t)(c1 + j) * stride];
                sd1[j] = sdv[sb0 + (c1 + j) * DI];
            }
        } else {
#pragma unroll
            for (int j = 0; j < 8; j++) { S1[j] = 0.f; sd1[j] = 0.f; }
        }
#pragma unroll
        for (int j = 0; j < 8; j++) {
            float P = exp2_f(Aval * sd0[j]);
            Sbuf[idx0 + (size_t)(g * 8 + j) * stride] = h;
            h = P * h + S0[j];
        }
#pragma unroll
        for (int j = 0; j < 8; j++) { S0[j] = S1[j]; sd0[j] = sd1[j]; }
    }
}

// Phase 3 lite: y = (yloc + sum_n C[n]*exp2(Aval[n]*cumd)*hinit[n]) * silu(res)
__global__ __launch_bounds__(256, 4) void scan_phase3_kernel(
        const unsigned* __restrict__ cy,
        const float* __restrict__ x_dbl, const float* __restrict__ Av,
        const float* __restrict__ Sbuf,
        const ushort* __restrict__ xz, ushort* __restrict__ y) {
    __shared__ __align__(16) float cs[CLEN * 16];   // C slab only, 1 KB
    const int tid = threadIdx.x;
    const int bc = blockIdx.x >> 1;
    const int d = ((blockIdx.x & 1) << 8) + tid;
    const int c = bc & (NCHUNK - 1);
    const int b = bc >> 6;
    const int m0 = b * LL + c * CLEN;
    {   // stage C columns (32..47) of chunk rows
        int tt = tid >> 4, k = tid & 15;
        cs[tt * 16 + k] = x_dbl[(size_t)(m0 + tt) * 64 + 32 + k];
    }
    float Aval[DS], hi[DS];
    size_t base = ((size_t)((b * NCHUNK + c) * DI + d)) * DS;
#pragma unroll
    for (int q = 0; q < 4; q++) {
        float4 a4 = *reinterpret_cast<const float4*>(&Av[d * DS + q * 4]);
        Aval[q*4+0] = a4.x; Aval[q*4+1] = a4.y; Aval[q*4+2] = a4.z; Aval[q*4+3] = a4.w;
        float4 h4 = *reinterpret_cast<const float4*>(&Sbuf[base + q * 4]);
        hi[q*4] = h4.x; hi[q*4+1] = h4.y; hi[q*4+2] = h4.z; hi[q*4+3] = h4.w;
    }
    const unsigned* cyp = cy + (size_t)m0 * DI + d;
    const ushort* rp = xz + (size_t)m0 * 1024 + 512 + d;
    ushort* yp = y + (size_t)m0 * DI + d;
    __syncthreads();
    unsigned cyw = cyp[0];
    float rv = bf2f(rp[0]);
#pragma unroll 4
    for (int t = 0; t < CLEN; t++) {
        unsigned cywn = 0; float rvn = 0.f;
        if (t + 1 < CLEN) {
            cywn = cyp[(size_t)(t + 1) * DI];
            rvn = bf2f(rp[(size_t)(t + 1) * 1024]);
        }
        float cd = bf2f((ushort)(cyw & 0xffffu));
        float yl = bf2f((ushort)(cyw >> 16));
        const float* cr = &cs[t * 16];
        float4 C0 = *reinterpret_cast<const float4*>(cr);
        float4 C1 = *reinterpret_cast<const float4*>(cr + 4);
        float4 C2 = *reinterpret_cast<const float4*>(cr + 8);
        float4 C3 = *reinterpret_cast<const float4*>(cr + 12);
        float a0, a1, a2, a3;
        a0  = exp2_f(Aval[0]  * cd) * hi[0]  * C0.x;
        a0 += exp2_f(Aval[1]  * cd) * hi[1]  * C0.y;
        a0 += exp2_f(Aval[2]  * cd) * hi[2]  * C0.z;
        a0 += exp2_f(Aval[3]  * cd) * hi[3]  * C0.w;
        a1  = exp2_f(Aval[4]  * cd) * hi[4]  * C1.x;
        a1 += exp2_f(Aval[5]  * cd) * hi[5]  * C1.y;
        a1 += exp2_f(Aval[6]  * cd) * hi[6]  * C1.z;
        a1 += exp2_f(Aval[7]  * cd) * hi[7]  * C1.w;
        a2  = exp2_f(Aval[8]  * cd) * hi[8]  * C2.x;
        a2 += exp2_f(Aval[9]  * cd) * hi[9]  * C2.y;
        a2 += exp2_f(Aval[10] * cd) * hi[10] * C2.z;
        a2 += exp2_f(Aval[11] * cd) * hi[11] * C2.w;
        a3  = exp2_f(Aval[12] * cd) * hi[12] * C3.x;
        a3 += exp2_f(Aval[13] * cd) * hi[13] * C3.y;
        a3 += exp2_f(Aval[14] * cd) * hi[14] * C3.z;
        a3 += exp2_f(Aval[15] * cd) * hi[15] * C3.w;
        float yv = yl + ((a0 + a1) + (a2 + a3));
        yp[(size_t)t * DI] = f2bf(yv * silu_f(rv));
        cyw = cywn; rv = rvn;
    }
}

// pool stage 1: partial[(b*8+slice)][dm] = sum over 128 l's
__global__ __launch_bounds__(256) void pool_partial_kernel(const ushort* __restrict__ ln,
                                                           float* __restrict__ partial) {
    int bs = blockIdx.x;            // 0..63
    int b = bs >> 3, sl = bs & 7;
    int t = threadIdx.x;            // dm
    int l0 = sl * 128;
    float s = 0.f;
    for (int l = 0; l < 128; l++) s += bf2f(ln[(size_t)(b * LL + l0 + l) * DM + t]);
    partial[(bs << 8) + t] = s;
}

__global__ void cls_kernel(const float* __restrict__ partial, const float* __restrict__ cw,
                           const float* __restrict__ cb, float* __restrict__ out) {
    int t = threadIdx.x;
    if (t >= NB * NC) return;
    int b = t / NC, c = t % NC;
    float s = 0.f;
    for (int k = 0; k < DM; k++) {
        float p = 0.f;
#pragma unroll
        for (int sl = 0; sl < 8; sl++) p += partial[((b * 8 + sl) << 8) + k];
        s += p * cw[c * DM + k];
    }
    out[t] = cb[c] + s * (1.0f / LL);
}

extern "C" void kernel_launch(void* const* d_in, const int* in_sizes, int n_in,
                              void* d_out, int out_size, void* d_ws, size_t ws_size,
                              hipStream_t stream) {
    const float* x       = (const float*)d_in[0];
    const float* input_w = (const float*)d_in[1];
    const float* input_b = (const float*)d_in[2];
    const float* ln_w    = (const float*)d_in[3];
    const float* ln_b    = (const float*)d_in[4];
    const float* ipw     = (const float*)d_in[5];
    const float* ipb     = (const float*)d_in[6];
    const float* cw      = (const float*)d_in[7];
    const float* cb      = (const float*)d_in[8];
    const float* xpw     = (const float*)d_in[9];
    const float* dtw     = (const float*)d_in[10];
    const float* dtb     = (const float*)d_in[11];
    const float* A_log   = (const float*)d_in[12];
    const float* Dp      = (const float*)d_in[13];
    const float* opw     = (const float*)d_in[14];
    const float* opb     = (const float*)d_in[15];
    const float* norm_w  = (const float*)d_in[16];
    const float* norm_b  = (const float*)d_in[17];
    const float* cls_w   = (const float*)d_in[18];
    const float* cls_b   = (const float*)d_in[19];
    float* out = (float*)d_out;
    float* ws = (float*)d_ws;

    float*    hres   = ws;                                   // MR*DM f32
    ushort*   xz     = (ushort*)(hres + (size_t)MR * DM);    // MR*1024 bf16
    ushort*   ub     = xz + (size_t)MR * 1024;               // MR*DI bf16
    float*    x_dbl  = (float*)(ub + (size_t)MR * DI);       // MR*64 f32
    float*    sdvb   = x_dbl + (size_t)MR * 64;              // NB*NCHUNK*DI f32
    float*    Sbuf   = sdvb + (size_t)NB * NCHUNK * DI;      // NB*NCHUNK*DI*DS f32
    float*    partial= Sbuf + (size_t)NB * NCHUNK * DI * DS; // 64*256 f32
    ushort*   ygate  = (ushort*)(partial + 64 * 256);        // MR*DI bf16
    ushort*   hln    = ygate + (size_t)MR * DI;              // MR*DM bf16
    ushort*   ipw_b  = hln + (size_t)MR * DM;                // IPW_N
    ushort*   xpw_b  = ipw_b + IPW_N;                        // XPW_N
    ushort*   opw_b  = xpw_b + XPW_N;                        // OPW_N
    float*    Avbuf  = (float*)(opw_b + OPW_N);              // AV_N f32
    unsigned* cy     = (unsigned*)(Avbuf + AV_N);            // MR*DI packed bf16x2

    convert_weights_kernel<<<(IPW_N + XPW_N + OPW_N + AV_N) / 256, 256, 0, stream>>>(
        ipw, xpw, opw, A_log, ipw_b, xpw_b, opw_b, Avbuf);
    input_ln_kernel<<<MR, 256, 0, stream>>>(x, input_w, input_b, ln_w, ln_b, hres, hln);

    for (int i = 0; i < NL; i++) {
        mfma_gemm_kernel<128, 128, 2, 2, 0><<<dim3(MR / 128, 1024 / 128), 256, 0, stream>>>(
            hln, DM, ipw_b + (size_t)i * 2 * DI * DM, ipb + (size_t)i * 2 * DI,
            xz, nullptr, 1024, DM);
        conv_silu_kernel<<<MR * DI / 8 / 256, 256, 0, stream>>>(xz, cw + i * DI * DC, cb + i * DI, ub);
        mfma_gemm_kernel<64, 64, 4, 1, 1><<<dim3(MR / 64, 1), 256, 0, stream>>>(
            ub, DI, xpw_b + (size_t)i * 64 * DI, nullptr, nullptr, x_dbl, 64, DI);
        scan_phase1_kernel<<<NB * NCHUNK * 2, 256, 0, stream>>>(
            ub, x_dbl, Avbuf + (size_t)i * DI * DS, dtw + i * DI * DR, dtb + i * DI,
            Dp + i * DI, sdvb, Sbuf, cy);
        scan_phase2_kernel<<<NB * DI * DS / 256, 256, 0, stream>>>(
            sdvb, Avbuf + (size_t)i * DI * DS, Sbuf);
        scan_phase3_kernel<<<NB * NCHUNK * 2, 256, 0, stream>>>(
            cy, x_dbl, Avbuf + (size_t)i * DI * DS, Sbuf, xz, ygate);
        const float* nlw = (i < NL - 1) ? (ln_w + (i + 1) * DM) : norm_w;
        const float* nlb = (i < NL - 1) ? (ln_b + (i + 1) * DM) : norm_b;
        outproj_ln_kernel<<<MR / 16, 256, 0, stream>>>(
            ygate, opw_b + (size_t)i * DM * DI, opb + (size_t)i * DM,
            hres, nlw, nlb, hln);
    }

    pool_partial_kernel<<<64, 256, 0, stream>>>(hln, partial);
    cls_kernel<<<1, 128, 0, stream>>>(partial, cls_w, cls_b, out);
}

// Round 16
// 413.179 us; speedup vs baseline: 1.0588x; 1.0049x over previous
//
#include <hip/hip_runtime.h>
#include <hip/hip_bf16.h>
#include <math.h>

#define DM 256      // D_MODEL
#define NL 4        // N_LAYERS
#define DI 512      // D_INNER
#define DS 16       // D_STATE
#define DC 4        // D_CONV
#define DR 16       // DT_RANK
#define NC 10       // NUM_CLASSES
#define NB 8        // B
#define LL 1024     // L
#define MR (NB*LL)  // 8192 rows
#define NCHUNK 64
#define CLEN 16

typedef __attribute__((ext_vector_type(4))) float f32x4;
typedef __attribute__((ext_vector_type(8))) short short8;

extern "C" __device__ float __ocml_native_exp2_f32(float);
__device__ __forceinline__ float exp2_f(float x) { return __ocml_native_exp2_f32(x); }
#define L2E 1.442695040888963f

__device__ __forceinline__ float silu_f(float x) {
    return x * (1.0f / (1.0f + __expf(-x)));
}
__device__ __forceinline__ float bf2f(ushort v) {
    union { unsigned u; float f; } c; c.u = ((unsigned)v) << 16; return c.f;
}
__device__ __forceinline__ ushort f2bf(float f) {   // round-to-nearest-even
    union { float f; unsigned u; } c; c.f = f;
    unsigned lsb = (c.u >> 16) & 1;
    return (ushort)((c.u + 0x7fffu + lsb) >> 16);
}
__device__ __forceinline__ void g2lds16(const void* g, void* l) {
    __builtin_amdgcn_global_load_lds((const __attribute__((address_space(1))) void*)g,
                                     (__attribute__((address_space(3))) void*)l, 16, 0, 0);
}

// ---- weight fp32 -> bf16 conversion + Aval table ----
#define IPW_N (NL*2*DI*DM)   // 1048576
#define XPW_N (NL*64*DI)     // 131072 (padded)
#define OPW_N (NL*DM*DI)     // 524288
#define AV_N  (NL*DI*DS)     // 32768
__global__ __launch_bounds__(256) void convert_weights_kernel(
        const float* __restrict__ ipw, const float* __restrict__ xpw,
        const float* __restrict__ opw, const float* __restrict__ A_log,
        ushort* __restrict__ ipw_b, ushort* __restrict__ xpw_b,
        ushort* __restrict__ opw_b, float* __restrict__ Av) {
    int t = blockIdx.x * 256 + threadIdx.x;
    if (t < IPW_N) { ipw_b[t] = f2bf(ipw[t]); return; }
    t -= IPW_N;
    if (t < XPW_N) {
        int l = t >> 15, r = (t >> 9) & 63, k = t & 511;
        xpw_b[t] = (r < 48) ? f2bf(xpw[((size_t)l * 48 + r) * DI + k]) : (ushort)0;
        return;
    }
    t -= XPW_N;
    if (t < OPW_N) { opw_b[t] = f2bf(opw[t]); return; }
    t -= OPW_N;
    if (t < AV_N) Av[t] = -__expf(A_log[t]) * L2E;
}

// fused input projection + layer-0 LN: v = x[m]*iw[t]+ib[t]; hres=v; hln=LN(v)
__global__ __launch_bounds__(256) void input_ln_kernel(
        const float* __restrict__ x, const float* __restrict__ iw,
        const float* __restrict__ ib,
        const float* __restrict__ lnw, const float* __restrict__ lnb,
        float* __restrict__ hres, ushort* __restrict__ hln) {
    int row = blockIdx.x, t = threadIdx.x;
    float v = x[row] * iw[t] + ib[t];
    float s = v, q = v * v;
#pragma unroll
    for (int o = 32; o >= 1; o >>= 1) { s += __shfl_xor(s, o); q += __shfl_xor(q, o); }
    __shared__ float red[8];
    int wid = t >> 6;
    if ((t & 63) == 0) { red[wid] = s; red[4 + wid] = q; }
    __syncthreads();
    s = red[0] + red[1] + red[2] + red[3];
    q = red[4] + red[5] + red[6] + red[7];
    float mu = s * (1.0f / DM);
    float var = q * (1.0f / DM) - mu * mu;
    float rs = rsqrtf(var + 1e-5f);
    hres[row * DM + t] = v;
    hln[row * DM + t] = f2bf((v - mu) * rs * lnw[t] + lnb[t]);
}

// ---- bf16 MFMA GEMM: C[M,N] = A[M,K] @ W[N,K]^T ----
// MODE 0: bf16 out + bias; MODE 1: f32 out
template<int BM, int BN, int WM, int WN, int MODE>
__global__ __launch_bounds__(256) void mfma_gemm_kernel(
        const ushort* __restrict__ A, int lda,
        const ushort* __restrict__ W,
        const float* __restrict__ bias,
        ushort* __restrict__ Cb, float* __restrict__ Cf, int ldc, int K) {
    constexpr int FM = BM / WM / 16;
    constexpr int FN = BN / WN / 16;
    __shared__ __align__(16) char smem[(BM + BN) * 128];
    const int tid = threadIdx.x;
    const int l = tid & 63, w = tid >> 6;
    const int wr = w / WN, wc = w % WN;
    const int bm = blockIdx.x * BM, bn = blockIdx.y * BN;
    const int ldw = K;

    f32x4 acc[FM][FN] = {};

    for (int k0 = 0; k0 < K; k0 += 64) {
#pragma unroll
        for (int i = 0; i < (BM * 128 / 16) / 256; i++) {
            int lin = (i * 256 + tid) * 16;
            int q = lin ^ (((lin >> 7) & 7) << 4);
            g2lds16(A + (size_t)(bm + (q >> 7)) * lda + k0 + ((q & 127) >> 1), smem + lin);
        }
#pragma unroll
        for (int i = 0; i < (BN * 128 / 16) / 256; i++) {
            int lin = (i * 256 + tid) * 16;
            int q = lin ^ (((lin >> 7) & 7) << 4);
            g2lds16(W + (size_t)(bn + (q >> 7)) * ldw + k0 + ((q & 127) >> 1),
                    smem + BM * 128 + lin);
        }
        __syncthreads();
        const int rl = l & 15;
        const int kb0 = ((l >> 4) << 3) * 2;
#pragma unroll
        for (int kk = 0; kk < 2; kk++) {
            short8 af[FM], bfr[FN];
#pragma unroll
            for (int m = 0; m < FM; m++) {
                int off = (wr * (BM / WM) + m * 16 + rl) * 128 + kk * 64 + kb0;
                off ^= ((off >> 7) & 7) << 4;
                af[m] = *(const short8*)(smem + off);
            }
#pragma unroll
            for (int n = 0; n < FN; n++) {
                int off = (wc * (BN / WN) + n * 16 + rl) * 128 + kk * 64 + kb0;
                off ^= ((off >> 7) & 7) << 4;
                bfr[n] = *(const short8*)(smem + BM * 128 + off);
            }
#pragma unroll
            for (int m = 0; m < FM; m++)
#pragma unroll
                for (int n = 0; n < FN; n++)
                    acc[m][n] = __builtin_amdgcn_mfma_f32_16x16x32_bf16(
                        af[m], bfr[n], acc[m][n], 0, 0, 0);
        }
        __syncthreads();
    }

    const int row0 = bm + wr * (BM / WM) + ((l >> 4) << 2);
    const int col0 = bn + wc * (BN / WN) + (l & 15);
#pragma unroll
    for (int m = 0; m < FM; m++) {
#pragma unroll
        for (int n = 0; n < FN; n++) {
            int col = col0 + n * 16;
            float bv = (MODE == 1) ? 0.f : bias[col];
#pragma unroll
            for (int r = 0; r < 4; r++) {
                size_t idx = (size_t)(row0 + m * 16 + r) * ldc + col;
                float v = acc[m][n][r];
                if (MODE == 0) Cb[idx] = f2bf(v + bv);
                else Cf[idx] = v;
            }
        }
    }
}

// ---- fused out_proj GEMM + residual + LayerNorm (BM=16, grid 512) ----
__global__ __launch_bounds__(256) void outproj_ln_kernel(
        const ushort* __restrict__ A,        // ygate [MR][512] bf16
        const ushort* __restrict__ W,        // opw_b [256][512] bf16
        const float* __restrict__ bias,      // opb [256]
        float* __restrict__ hres,            // residual stream f32 [MR][256]
        const float* __restrict__ lnw, const float* __restrict__ lnb,
        ushort* __restrict__ hln) {
    constexpr int K = DI;
    __shared__ __align__(16) char smem[(16 + 256) * 128];
    const int tid = threadIdx.x;
    const int l = tid & 63, w = tid >> 6;   // w = col-quarter
    const int bm = blockIdx.x * 16;

    f32x4 acc[4] = {};

    for (int k0 = 0; k0 < K; k0 += 64) {
        if (tid < 128) {   // A tile: 16 rows x 128B
            int lin = tid * 16;
            int q = lin ^ (((lin >> 7) & 7) << 4);
            g2lds16(A + (size_t)(bm + (q >> 7)) * K + k0 + ((q & 127) >> 1), smem + lin);
        }
#pragma unroll
        for (int i = 0; i < 8; i++) {   // W tile: 256 rows
            int lin = (i * 256 + tid) * 16;
            int q = lin ^ (((lin >> 7) & 7) << 4);
            g2lds16(W + (size_t)(q >> 7) * K + k0 + ((q & 127) >> 1), smem + 16 * 128 + lin);
        }
        __syncthreads();
        const int rl = l & 15;
        const int kb0 = ((l >> 4) << 3) * 2;
#pragma unroll
        for (int kk = 0; kk < 2; kk++) {
            short8 af;
            {
                int off = rl * 128 + kk * 64 + kb0;
                off ^= ((off >> 7) & 7) << 4;
                af = *(const short8*)(smem + off);
            }
            short8 bfr[4];
#pragma unroll
            for (int n = 0; n < 4; n++) {
                int off = (w * 64 + n * 16 + rl) * 128 + kk * 64 + kb0;
                off ^= ((off >> 7) & 7) << 4;
                bfr[n] = *(const short8*)(smem + 16 * 128 + off);
            }
#pragma unroll
            for (int n = 0; n < 4; n++)
                acc[n] = __builtin_amdgcn_mfma_f32_16x16x32_bf16(af, bfr[n], acc[n], 0, 0, 0);
        }
        __syncthreads();
    }

    const int r0 = (l >> 4) << 2;          // 0,4,8,12
    const int col0 = w * 64 + (l & 15);
    float vv[4][4];
    float s[4], q[4];
#pragma unroll
    for (int r = 0; r < 4; r++) { s[r] = 0.f; q[r] = 0.f; }
#pragma unroll
    for (int n = 0; n < 4; n++) {
        int col = col0 + n * 16;
        float bv = bias[col];
#pragma unroll
        for (int r = 0; r < 4; r++) {
            int row = bm + r0 + r;
            float x = acc[n][r] + bv + hres[(size_t)row * DM + col];
            vv[n][r] = x;
            s[r] += x;
            q[r] += x * x;
        }
    }
#pragma unroll
    for (int o = 1; o < 16; o <<= 1) {
#pragma unroll
        for (int r = 0; r < 4; r++) {
            s[r] += __shfl_xor(s[r], o);
            q[r] += __shfl_xor(q[r], o);
        }
    }
    float* red  = (float*)smem;            // [16][4]
    float* redq = red + 64;                // [16][4]
    if ((l & 15) == 0) {
#pragma unroll
        for (int r = 0; r < 4; r++) {
            int rl2 = r0 + r;
            red[rl2 * 4 + w] = s[r];
            redq[rl2 * 4 + w] = q[r];
        }
    }
    __syncthreads();
    float mu[4], rs[4];
#pragma unroll
    for (int r = 0; r < 4; r++) {
        int rl2 = r0 + r;
        float ts = red[rl2 * 4] + red[rl2 * 4 + 1] + red[rl2 * 4 + 2] + red[rl2 * 4 + 3];
        float tq = redq[rl2 * 4] + redq[rl2 * 4 + 1] + redq[rl2 * 4 + 2] + redq[rl2 * 4 + 3];
        mu[r] = ts * (1.0f / DM);
        float var = tq * (1.0f / DM) - mu[r] * mu[r];
        rs[r] = rsqrtf(var + 1e-5f);
    }
#pragma unroll
    for (int n = 0; n < 4; n++) {
        int col = col0 + n * 16;
        float lw = lnw[col], lb = lnb[col];
#pragma unroll
        for (int r = 0; r < 4; r++) {
            int row = bm + r0 + r;
            hres[(size_t)row * DM + col] = vv[n][r];
            hln[(size_t)row * DM + col] = f2bf((vv[n][r] - mu[r]) * rs[r] * lw + lb);
        }
    }
}

// depthwise causal conv (K=4) + SiLU; xz bf16 (ld 1024, cols 0..511) -> u bf16
__global__ __launch_bounds__(256) void conv_silu_kernel(const ushort* __restrict__ xz,
        const float* __restrict__ cw, const float* __restrict__ cb, ushort* __restrict__ u) {
    int t = blockIdx.x * 256 + threadIdx.x;   // MR*DI/8 threads
    int d8 = (t & 63) << 3;
    int m = t >> 6;
    int l = m & (LL - 1);
    const short8 zr = {0, 0, 0, 0, 0, 0, 0, 0};
    const size_t base = (size_t)m * 1024 + d8;
    short8 r3 = *(const short8*)(xz + base);
    short8 r2 = (l >= 1) ? *(const short8*)(xz + base - 1024) : zr;
    short8 r1 = (l >= 2) ? *(const short8*)(xz + base - 2048) : zr;
    short8 r0 = (l >= 3) ? *(const short8*)(xz + base - 3072) : zr;
    short8 o;
#pragma unroll
    for (int j = 0; j < 8; j++) {
        int d = d8 + j;
        float4 w4 = *reinterpret_cast<const float4*>(&cw[d * 4]);
        float a = cb[d] + w4.w * bf2f((ushort)r3[j]);
        a += w4.z * bf2f((ushort)r2[j]);
        a += w4.y * bf2f((ushort)r1[j]);
        a += w4.x * bf2f((ushort)r0[j]);
        o[j] = (short)f2bf(silu_f(a));
    }
    *(short8*)(u + (size_t)m * DI + d8) = o;
}

// ---- chunked parallel scan, algebraic split ----
// Phase 1: chunk-local pass. Outputs: S, sdv, packed (cumd,yloc) bf16x2.
__global__ __launch_bounds__(256, 4) void scan_phase1_kernel(
        const ushort* __restrict__ u, const float* __restrict__ x_dbl,
        const float* __restrict__ Av,
        const float* __restrict__ dtw, const float* __restrict__ dtb,
        const float* __restrict__ Dp,
        float* __restrict__ sdv, float* __restrict__ Sbuf,
        unsigned* __restrict__ cy) {
    __shared__ __align__(16) float xs[CLEN * 64];
    const int tid = threadIdx.x;
    const int bc = blockIdx.x >> 1;
    const int d = ((blockIdx.x & 1) << 8) + tid;
    const int c = bc & (NCHUNK - 1);
    const int b = bc >> 6;
    const int m0 = b * LL + c * CLEN;
    *reinterpret_cast<float4*>(&xs[tid * 4]) =
        *reinterpret_cast<const float4*>(&x_dbl[(size_t)m0 * 64 + tid * 4]);

    float Aval[DS], h[DS], wreg[DR];
#pragma unroll
    for (int q = 0; q < 4; q++) {
        float4 a4 = *reinterpret_cast<const float4*>(&Av[d * DS + q * 4]);
        Aval[q*4+0] = a4.x; Aval[q*4+1] = a4.y; Aval[q*4+2] = a4.z; Aval[q*4+3] = a4.w;
        float4 w4 = *reinterpret_cast<const float4*>(&dtw[d * DR + q * 4]);
        wreg[q*4] = w4.x; wreg[q*4+1] = w4.y; wreg[q*4+2] = w4.z; wreg[q*4+3] = w4.w;
    }
    float dbv = dtb[d];
    float Dval = Dp[d];
#pragma unroll
    for (int n = 0; n < DS; n++) h[n] = 0.f;
    const ushort* up = u + (size_t)m0 * DI + d;
    unsigned* cyp = cy + (size_t)m0 * DI + d;
    float sd = 0.f;
    __syncthreads();
    float uv = bf2f(up[0]);
    for (int t = 0; t < CLEN; t++) {
        float uvn = (t + 1 < CLEN) ? bf2f(up[(size_t)(t + 1) * DI]) : 0.f;
        const float* xr = &xs[t * 64];
        float4 x0 = *reinterpret_cast<const float4*>(xr);
        float4 x1 = *reinterpret_cast<const float4*>(xr + 4);
        float4 x2 = *reinterpret_cast<const float4*>(xr + 8);
        float4 x3 = *reinterpret_cast<const float4*>(xr + 12);
        float4 B0 = *reinterpret_cast<const float4*>(xr + 16);
        float4 B1 = *reinterpret_cast<const float4*>(xr + 20);
        float4 B2 = *reinterpret_cast<const float4*>(xr + 24);
        float4 B3 = *reinterpret_cast<const float4*>(xr + 28);
        float4 C0 = *reinterpret_cast<const float4*>(xr + 32);
        float4 C1 = *reinterpret_cast<const float4*>(xr + 36);
        float4 C2 = *reinterpret_cast<const float4*>(xr + 40);
        float4 C3 = *reinterpret_cast<const float4*>(xr + 44);
        float p0 = dbv + wreg[0]*x0.x + wreg[1]*x0.y + wreg[2]*x0.z + wreg[3]*x0.w;
        float p1 = wreg[4]*x1.x + wreg[5]*x1.y + wreg[6]*x1.z + wreg[7]*x1.w;
        float p2 = wreg[8]*x2.x + wreg[9]*x2.y + wreg[10]*x2.z + wreg[11]*x2.w;
        float p3 = wreg[12]*x3.x + wreg[13]*x3.y + wreg[14]*x3.z + wreg[15]*x3.w;
        float z = (p0 + p1) + (p2 + p3);
        float dv = (z > 20.0f) ? z : __logf(1.0f + __expf(z));
        sd += dv;
        float du = dv * uv;
        float a0, a1, a2, a3;
        h[0]  = exp2_f(dv*Aval[0])  * h[0]  + du * B0.x;  a0  = h[0]  * C0.x;
        h[1]  = exp2_f(dv*Aval[1])  * h[1]  + du * B0.y;  a0 += h[1]  * C0.y;
        h[2]  = exp2_f(dv*Aval[2])  * h[2]  + du * B0.z;  a0 += h[2]  * C0.z;
        h[3]  = exp2_f(dv*Aval[3])  * h[3]  + du * B0.w;  a0 += h[3]  * C0.w;
        h[4]  = exp2_f(dv*Aval[4])  * h[4]  + du * B1.x;  a1  = h[4]  * C1.x;
        h[5]  = exp2_f(dv*Aval[5])  * h[5]  + du * B1.y;  a1 += h[5]  * C1.y;
        h[6]  = exp2_f(dv*Aval[6])  * h[6]  + du * B1.z;  a1 += h[6]  * C1.z;
        h[7]  = exp2_f(dv*Aval[7])  * h[7]  + du * B1.w;  a1 += h[7]  * C1.w;
        h[8]  = exp2_f(dv*Aval[8])  * h[8]  + du * B2.x;  a2  = h[8]  * C2.x;
        h[9]  = exp2_f(dv*Aval[9])  * h[9]  + du * B2.y;  a2 += h[9]  * C2.y;
        h[10] = exp2_f(dv*Aval[10]) * h[10] + du * B2.z;  a2 += h[10] * C2.z;
        h[11] = exp2_f(dv*Aval[11]) * h[11] + du * B2.w;  a2 += h[11] * C2.w;
        h[12] = exp2_f(dv*Aval[12]) * h[12] + du * B3.x;  a3  = h[12] * C3.x;
        h[13] = exp2_f(dv*Aval[13]) * h[13] + du * B3.y;  a3 += h[13] * C3.y;
        h[14] = exp2_f(dv*Aval[14]) * h[14] + du * B3.z;  a3 += h[14] * C3.z;
        h[15] = exp2_f(dv*Aval[15]) * h[15] + du * B3.w;  a3 += h[15] * C3.w;
        float yv = ((a0 + a1) + (a2 + a3)) + Dval * uv;
        cyp[(size_t)t * DI] = (unsigned)f2bf(sd) | ((unsigned)f2bf(yv) << 16);
        uv = uvn;
    }
    size_t base = ((size_t)((b * NCHUNK + c) * DI + d)) * DS;
#pragma unroll
    for (int q = 0; q < 4; q++)
        *reinterpret_cast<float4*>(&Sbuf[base + q * 4]) =
            make_float4(h[q*4], h[q*4+1], h[q*4+2], h[q*4+3]);
    sdv[(b * NCHUNK + c) * DI + d] = sd;
}

// Phase 2: per (b,d,n) thread; batch-8 deep prefetch pipeline.
__global__ __launch_bounds__(256) void scan_phase2_kernel(
        const float* __restrict__ sdv, const float* __restrict__ Av,
        float* __restrict__ Sbuf) {
    int gid = blockIdx.x * 256 + threadIdx.x;
    int dn = gid & (DI * DS - 1);
    int b = gid >> 13;
    int n = dn & 15, d = dn >> 4;
    float Aval = Av[d * DS + n];
    size_t idx0 = (size_t)b * NCHUNK * DI * DS + dn;
    const size_t stride = (size_t)DI * DS;
    int sb0 = b * NCHUNK * DI + d;
    float h = 0.f;
    float S0[8], sd0[8];
#pragma unroll
    for (int j = 0; j < 8; j++) {
        S0[j] = Sbuf[idx0 + (size_t)j * stride];
        sd0[j] = sdv[sb0 + j * DI];
    }
    for (int g = 0; g < NCHUNK / 8; g++) {
        float S1[8], sd1[8];
        if (g < NCHUNK / 8 - 1) {
            int c1 = g * 8 + 8;
#pragma unroll
            for (int j = 0; j < 8; j++) {
                S1[j] = Sbuf[idx0 + (size_t)(c1 + j) * stride];
                sd1[j] = sdv[sb0 + (c1 + j) * DI];
            }
        } else {
#pragma unroll
            for (int j = 0; j < 8; j++) { S1[j] = 0.f; sd1[j] = 0.f; }
        }
#pragma unroll
        for (int j = 0; j < 8; j++) {
            float P = exp2_f(Aval * sd0[j]);
            Sbuf[idx0 + (size_t)(g * 8 + j) * stride] = h;
            h = P * h + S0[j];
        }
#pragma unroll
        for (int j = 0; j < 8; j++) { S0[j] = S1[j]; sd0[j] = sd1[j]; }
    }
}

// Phase 3 lite: y = (yloc + sum_n C[n]*exp2(Aval[n]*cumd)*hinit[n]) * silu(res)
__global__ __launch_bounds__(256, 4) void scan_phase3_kernel(
        const unsigned* __restrict__ cy,
        const float* __restrict__ x_dbl, const float* __restrict__ Av,
        const float* __restrict__ Sbuf,
        const ushort* __restrict__ xz, ushort* __restrict__ y) {
    __shared__ __align__(16) float cs[CLEN * 16];   // C slab only, 1 KB
    const int tid = threadIdx.x;
    const int bc = blockIdx.x >> 1;
    const int d = ((blockIdx.x & 1) << 8) + tid;
    const int c = bc & (NCHUNK - 1);
    const int b = bc >> 6;
    const int m0 = b * LL + c * CLEN;
    {   // stage C columns (32..47) of chunk rows
        int tt = tid >> 4, k = tid & 15;
        cs[tt * 16 + k] = x_dbl[(size_t)(m0 + tt) * 64 + 32 + k];
    }
    float Aval[DS], hi[DS];
    size_t base = ((size_t)((b * NCHUNK + c) * DI + d)) * DS;
#pragma unroll
    for (int q = 0; q < 4; q++) {
        float4 a4 = *reinterpret_cast<const float4*>(&Av[d * DS + q * 4]);
        Aval[q*4+0] = a4.x; Aval[q*4+1] = a4.y; Aval[q*4+2] = a4.z; Aval[q*4+3] = a4.w;
        float4 h4 = *reinterpret_cast<const float4*>(&Sbuf[base + q * 4]);
        hi[q*4] = h4.x; hi[q*4+1] = h4.y; hi[q*4+2] = h4.z; hi[q*4+3] = h4.w;
    }
    const unsigned* cyp = cy + (size_t)m0 * DI + d;
    const ushort* rp = xz + (size_t)m0 * 1024 + 512 + d;
    ushort* yp = y + (size_t)m0 * DI + d;
    __syncthreads();
    unsigned cyw = cyp[0];
    float rv = bf2f(rp[0]);
#pragma unroll 4
    for (int t = 0; t < CLEN; t++) {
        unsigned cywn = 0; float rvn = 0.f;
        if (t + 1 < CLEN) {
            cywn = cyp[(size_t)(t + 1) * DI];
            rvn = bf2f(rp[(size_t)(t + 1) * 1024]);
        }
        float cd = bf2f((ushort)(cyw & 0xffffu));
        float yl = bf2f((ushort)(cyw >> 16));
        const float* cr = &cs[t * 16];
        float4 C0 = *reinterpret_cast<const float4*>(cr);
        float4 C1 = *reinterpret_cast<const float4*>(cr + 4);
        float4 C2 = *reinterpret_cast<const float4*>(cr + 8);
        float4 C3 = *reinterpret_cast<const float4*>(cr + 12);
        float a0, a1, a2, a3;
        a0  = exp2_f(Aval[0]  * cd) * hi[0]  * C0.x;
        a0 += exp2_f(Aval[1]  * cd) * hi[1]  * C0.y;
        a0 += exp2_f(Aval[2]  * cd) * hi[2]  * C0.z;
        a0 += exp2_f(Aval[3]  * cd) * hi[3]  * C0.w;
        a1  = exp2_f(Aval[4]  * cd) * hi[4]  * C1.x;
        a1 += exp2_f(Aval[5]  * cd) * hi[5]  * C1.y;
        a1 += exp2_f(Aval[6]  * cd) * hi[6]  * C1.z;
        a1 += exp2_f(Aval[7]  * cd) * hi[7]  * C1.w;
        a2  = exp2_f(Aval[8]  * cd) * hi[8]  * C2.x;
        a2 += exp2_f(Aval[9]  * cd) * hi[9]  * C2.y;
        a2 += exp2_f(Aval[10] * cd) * hi[10] * C2.z;
        a2 += exp2_f(Aval[11] * cd) * hi[11] * C2.w;
        a3  = exp2_f(Aval[12] * cd) * hi[12] * C3.x;
        a3 += exp2_f(Aval[13] * cd) * hi[13] * C3.y;
        a3 += exp2_f(Aval[14] * cd) * hi[14] * C3.z;
        a3 += exp2_f(Aval[15] * cd) * hi[15] * C3.w;
        float yv = yl + ((a0 + a1) + (a2 + a3));
        yp[(size_t)t * DI] = f2bf(yv * silu_f(rv));
        cyw = cywn; rv = rvn;
    }
}

// pool stage 1: partial[(b*8+slice)][dm] = sum over 128 l's
__global__ __launch_bounds__(256) void pool_partial_kernel(const ushort* __restrict__ ln,
                                                           float* __restrict__ partial) {
    int bs = blockIdx.x;            // 0..63
    int b = bs >> 3, sl = bs & 7;
    int t = threadIdx.x;            // dm
    int l0 = sl * 128;
    float s = 0.f;
    for (int l = 0; l < 128; l++) s += bf2f(ln[(size_t)(b * LL + l0 + l) * DM + t]);
    partial[(bs << 8) + t] = s;
}

__global__ void cls_kernel(const float* __restrict__ partial, const float* __restrict__ cw,
                           const float* __restrict__ cb, float* __restrict__ out) {
    int t = threadIdx.x;
    if (t >= NB * NC) return;
    int b = t / NC, c = t % NC;
    float s = 0.f;
    for (int k = 0; k < DM; k++) {
        float p = 0.f;
#pragma unroll
        for (int sl = 0; sl < 8; sl++) p += partial[((b * 8 + sl) << 8) + k];
        s += p * cw[c * DM + k];
    }
    out[t] = cb[c] + s * (1.0f / LL);
}

extern "C" void kernel_launch(void* const* d_in, const int* in_sizes, int n_in,
                              void* d_out, int out_size, void* d_ws, size_t ws_size,
                              hipStream_t stream) {
    const float* x       = (const float*)d_in[0];
    const float* input_w = (const float*)d_in[1];
    const float* input_b = (const float*)d_in[2];
    const float* ln_w    = (const float*)d_in[3];
    const float* ln_b    = (const float*)d_in[4];
    const float* ipw     = (const float*)d_in[5];
    const float* ipb     = (const float*)d_in[6];
    const float* cw      = (const float*)d_in[7];
    const float* cb      = (const float*)d_in[8];
    const float* xpw     = (const float*)d_in[9];
    const float* dtw     = (const float*)d_in[10];
    const float* dtb     = (const float*)d_in[11];
    const float* A_log   = (const float*)d_in[12];
    const float* Dp      = (const float*)d_in[13];
    const float* opw     = (const float*)d_in[14];
    const float* opb     = (const float*)d_in[15];
    const float* norm_w  = (const float*)d_in[16];
    const float* norm_b  = (const float*)d_in[17];
    const float* cls_w   = (const float*)d_in[18];
    const float* cls_b   = (const float*)d_in[19];
    float* out = (float*)d_out;
    float* ws = (float*)d_ws;

    float*    hres   = ws;                                   // MR*DM f32
    ushort*   xz     = (ushort*)(hres + (size_t)MR * DM);    // MR*1024 bf16
    ushort*   ub     = xz + (size_t)MR * 1024;               // MR*DI bf16
    float*    x_dbl  = (float*)(ub + (size_t)MR * DI);       // MR*64 f32
    float*    sdvb   = x_dbl + (size_t)MR * 64;              // NB*NCHUNK*DI f32
    float*    Sbuf   = sdvb + (size_t)NB * NCHUNK * DI;      // NB*NCHUNK*DI*DS f32
    float*    partial= Sbuf + (size_t)NB * NCHUNK * DI * DS; // 64*256 f32
    ushort*   ygate  = (ushort*)(partial + 64 * 256);        // MR*DI bf16
    ushort*   hln    = ygate + (size_t)MR * DI;              // MR*DM bf16
    ushort*   ipw_b  = hln + (size_t)MR * DM;                // IPW_N
    ushort*   xpw_b  = ipw_b + IPW_N;                        // XPW_N
    ushort*   opw_b  = xpw_b + XPW_N;                        // OPW_N
    float*    Avbuf  = (float*)(opw_b + OPW_N);              // AV_N f32
    unsigned* cy     = (unsigned*)(Avbuf + AV_N);            // MR*DI packed bf16x2

    convert_weights_kernel<<<(IPW_N + XPW_N + OPW_N + AV_N) / 256, 256, 0, stream>>>(
        ipw, xpw, opw, A_log, ipw_b, xpw_b, opw_b, Avbuf);
    input_ln_kernel<<<MR, 256, 0, stream>>>(x, input_w, input_b, ln_w, ln_b, hres, hln);

    for (int i = 0; i < NL; i++) {
        mfma_gemm_kernel<128, 128, 2, 2, 0><<<dim3(MR / 128, 1024 / 128), 256, 0, stream>>>(
            hln, DM, ipw_b + (size_t)i * 2 * DI * DM, ipb + (size_t)i * 2 * DI,
            xz, nullptr, 1024, DM);
        conv_silu_kernel<<<MR * DI / 8 / 256, 256, 0, stream>>>(xz, cw + i * DI * DC, cb + i * DI, ub);
        mfma_gemm_kernel<32, 64, 2, 2, 1><<<dim3(MR / 32, 1), 256, 0, stream>>>(
            ub, DI, xpw_b + (size_t)i * 64 * DI, nullptr, nullptr, x_dbl, 64, DI);
        scan_phase1_kernel<<<NB * NCHUNK * 2, 256, 0, stream>>>(
            ub, x_dbl, Avbuf + (size_t)i * DI * DS, dtw + i * DI * DR, dtb + i * DI,
            Dp + i * DI, sdvb, Sbuf, cy);
        scan_phase2_kernel<<<NB * DI * DS / 256, 256, 0, stream>>>(
            sdvb, Avbuf + (size_t)i * DI * DS, Sbuf);
        scan_phase3_kernel<<<NB * NCHUNK * 2, 256, 0, stream>>>(
            cy, x_dbl, Avbuf + (size_t)i * DI * DS, Sbuf, xz, ygate);
        const float* nlw = (i < NL - 1) ? (ln_w + (i + 1) * DM) : norm_w;
        const float* nlb = (i < NL - 1) ? (ln_b + (i + 1) * DM) : norm_b;
        outproj_ln_kernel<<<MR / 16, 256, 0, stream>>>(
            ygate, opw_b + (size_t)i * DM * DI, opb + (size_t)i * DM,
            hres, nlw, nlb, hln);
    }

    pool_partial_kernel<<<64, 256, 0, stream>>>(hln, partial);
    cls_kernel<<<1, 128, 0, stream>>>(partial, cls_w, cls_b, out);
}

// Round 17
// 411.157 us; speedup vs baseline: 1.0641x; 1.0049x over previous
//
#include <hip/hip_runtime.h>
#include <hip/hip_bf16.h>
#include <math.h>

#define DM 256      // D_MODEL
#define NL 4        // N_LAYERS
#define DI 512      // D_INNER
#define DS 16       // D_STATE
#define DC 4        // D_CONV
#define DR 16       // DT_RANK
#define NC 10       // NUM_CLASSES
#define NB 8        // B
#define LL 1024     // L
#define MR (NB*LL)  // 8192 rows
#define NCHUNK 64
#define CLEN 16

typedef __attribute__((ext_vector_type(4))) float f32x4;
typedef __attribute__((ext_vector_type(8))) short short8;

extern "C" __device__ float __ocml_native_exp2_f32(float);
__device__ __forceinline__ float exp2_f(float x) { return __ocml_native_exp2_f32(x); }
#define L2E 1.442695040888963f

__device__ __forceinline__ float silu_f(float x) {
    return x * (1.0f / (1.0f + __expf(-x)));
}
__device__ __forceinline__ float bf2f(ushort v) {
    union { unsigned u; float f; } c; c.u = ((unsigned)v) << 16; return c.f;
}
__device__ __forceinline__ ushort f2bf(float f) {   // round-to-nearest-even
    union { float f; unsigned u; } c; c.f = f;
    unsigned lsb = (c.u >> 16) & 1;
    return (ushort)((c.u + 0x7fffu + lsb) >> 16);
}
__device__ __forceinline__ void g2lds16(const void* g, void* l) {
    __builtin_amdgcn_global_load_lds((const __attribute__((address_space(1))) void*)g,
                                     (__attribute__((address_space(3))) void*)l, 16, 0, 0);
}

// ---- weight fp32 -> bf16 conversion + Aval table ----
#define IPW_N (NL*2*DI*DM)   // 1048576
#define XPW_N (NL*64*DI)     // 131072 (padded)
#define OPW_N (NL*DM*DI)     // 524288
#define AV_N  (NL*DI*DS)     // 32768
__global__ __launch_bounds__(256) void convert_weights_kernel(
        const float* __restrict__ ipw, const float* __restrict__ xpw,
        const float* __restrict__ opw, const float* __restrict__ A_log,
        ushort* __restrict__ ipw_b, ushort* __restrict__ xpw_b,
        ushort* __restrict__ opw_b, float* __restrict__ Av) {
    int t = blockIdx.x * 256 + threadIdx.x;
    if (t < IPW_N) { ipw_b[t] = f2bf(ipw[t]); return; }
    t -= IPW_N;
    if (t < XPW_N) {
        int l = t >> 15, r = (t >> 9) & 63, k = t & 511;
        xpw_b[t] = (r < 48) ? f2bf(xpw[((size_t)l * 48 + r) * DI + k]) : (ushort)0;
        return;
    }
    t -= XPW_N;
    if (t < OPW_N) { opw_b[t] = f2bf(opw[t]); return; }
    t -= OPW_N;
    if (t < AV_N) Av[t] = -__expf(A_log[t]) * L2E;
}

// fused input projection + layer-0 LN: v = x[m]*iw[t]+ib[t]; hres=v; hln=LN(v)
__global__ __launch_bounds__(256) void input_ln_kernel(
        const float* __restrict__ x, const float* __restrict__ iw,
        const float* __restrict__ ib,
        const float* __restrict__ lnw, const float* __restrict__ lnb,
        float* __restrict__ hres, ushort* __restrict__ hln) {
    int row = blockIdx.x, t = threadIdx.x;
    float v = x[row] * iw[t] + ib[t];
    float s = v, q = v * v;
#pragma unroll
    for (int o = 32; o >= 1; o >>= 1) { s += __shfl_xor(s, o); q += __shfl_xor(q, o); }
    __shared__ float red[8];
    int wid = t >> 6;
    if ((t & 63) == 0) { red[wid] = s; red[4 + wid] = q; }
    __syncthreads();
    s = red[0] + red[1] + red[2] + red[3];
    q = red[4] + red[5] + red[6] + red[7];
    float mu = s * (1.0f / DM);
    float var = q * (1.0f / DM) - mu * mu;
    float rs = rsqrtf(var + 1e-5f);
    hres[row * DM + t] = v;
    hln[row * DM + t] = f2bf((v - mu) * rs * lnw[t] + lnb[t]);
}

// ---- bf16 MFMA GEMM: C[M,N] = A[M,K] @ W[N,K]^T ----
// MODE 0: bf16 out + bias; MODE 1: f32 out
template<int BM, int BN, int WM, int WN, int MODE>
__global__ __launch_bounds__(256) void mfma_gemm_kernel(
        const ushort* __restrict__ A, int lda,
        const ushort* __restrict__ W,
        const float* __restrict__ bias,
        ushort* __restrict__ Cb, float* __restrict__ Cf, int ldc, int K) {
    constexpr int FM = BM / WM / 16;
    constexpr int FN = BN / WN / 16;
    __shared__ __align__(16) char smem[(BM + BN) * 128];
    const int tid = threadIdx.x;
    const int l = tid & 63, w = tid >> 6;
    const int wr = w / WN, wc = w % WN;
    const int bm = blockIdx.x * BM, bn = blockIdx.y * BN;
    const int ldw = K;

    f32x4 acc[FM][FN] = {};

    for (int k0 = 0; k0 < K; k0 += 64) {
#pragma unroll
        for (int i = 0; i < (BM * 128 / 16) / 256; i++) {
            int lin = (i * 256 + tid) * 16;
            int q = lin ^ (((lin >> 7) & 7) << 4);
            g2lds16(A + (size_t)(bm + (q >> 7)) * lda + k0 + ((q & 127) >> 1), smem + lin);
        }
#pragma unroll
        for (int i = 0; i < (BN * 128 / 16) / 256; i++) {
            int lin = (i * 256 + tid) * 16;
            int q = lin ^ (((lin >> 7) & 7) << 4);
            g2lds16(W + (size_t)(bn + (q >> 7)) * ldw + k0 + ((q & 127) >> 1),
                    smem + BM * 128 + lin);
        }
        __syncthreads();
        const int rl = l & 15;
        const int kb0 = ((l >> 4) << 3) * 2;
#pragma unroll
        for (int kk = 0; kk < 2; kk++) {
            short8 af[FM], bfr[FN];
#pragma unroll
            for (int m = 0; m < FM; m++) {
                int off = (wr * (BM / WM) + m * 16 + rl) * 128 + kk * 64 + kb0;
                off ^= ((off >> 7) & 7) << 4;
                af[m] = *(const short8*)(smem + off);
            }
#pragma unroll
            for (int n = 0; n < FN; n++) {
                int off = (wc * (BN / WN) + n * 16 + rl) * 128 + kk * 64 + kb0;
                off ^= ((off >> 7) & 7) << 4;
                bfr[n] = *(const short8*)(smem + BM * 128 + off);
            }
#pragma unroll
            for (int m = 0; m < FM; m++)
#pragma unroll
                for (int n = 0; n < FN; n++)
                    acc[m][n] = __builtin_amdgcn_mfma_f32_16x16x32_bf16(
                        af[m], bfr[n], acc[m][n], 0, 0, 0);
        }
        __syncthreads();
    }

    const int row0 = bm + wr * (BM / WM) + ((l >> 4) << 2);
    const int col0 = bn + wc * (BN / WN) + (l & 15);
#pragma unroll
    for (int m = 0; m < FM; m++) {
#pragma unroll
        for (int n = 0; n < FN; n++) {
            int col = col0 + n * 16;
            float bv = (MODE == 1) ? 0.f : bias[col];
#pragma unroll
            for (int r = 0; r < 4; r++) {
                size_t idx = (size_t)(row0 + m * 16 + r) * ldc + col;
                float v = acc[m][n][r];
                if (MODE == 0) Cb[idx] = f2bf(v + bv);
                else Cf[idx] = v;
            }
        }
    }
}

// ---- x_proj GEMM with inline conv+SiLU; also writes u to global ----
// x_dbl[M,64] = u[M,512] @ xpw^T, u = silu(conv(xz u-half)) computed inline.
__global__ __launch_bounds__(256) void xproj_conv_kernel(
        const ushort* __restrict__ xz,       // [MR][1024]
        const float* __restrict__ cw,        // [DI][4]
        const float* __restrict__ cb,        // [DI]
        const ushort* __restrict__ W,        // xpw_b [64][512]
        ushort* __restrict__ u,              // [MR][512] out (for scan_phase1)
        float* __restrict__ Cf) {            // x_dbl [MR][64]
    constexpr int BM = 32, BN = 64, K = DI;
    __shared__ __align__(16) char smem[(BM + BN) * 128];
    const int tid = threadIdx.x;
    const int l = tid & 63, w = tid >> 6;
    const int wr = w >> 1, wc = w & 1;       // WM=2, WN=2
    const int bm = blockIdx.x * BM;
    const short8 zr = {0, 0, 0, 0, 0, 0, 0, 0};

    f32x4 acc[2] = {};                        // FM=1, FN=2

    for (int k0 = 0; k0 < K; k0 += 64) {
        {   // A-tile: conv+silu for 32 rows x 64 cols; write u; stage LDS (swizzled)
            int row = tid >> 3, grp = tid & 7;
            int gcol = k0 + grp * 8;
            size_t base = (size_t)(bm + row) * 1024 + gcol;
            int lrow = (bm + row) & (LL - 1);
            short8 r3 = *(const short8*)(xz + base);
            short8 r2 = (lrow >= 1) ? *(const short8*)(xz + base - 1024) : zr;
            short8 r1 = (lrow >= 2) ? *(const short8*)(xz + base - 2048) : zr;
            short8 r0 = (lrow >= 3) ? *(const short8*)(xz + base - 3072) : zr;
            short8 o;
#pragma unroll
            for (int j = 0; j < 8; j++) {
                int dd = gcol + j;
                float4 w4 = *reinterpret_cast<const float4*>(&cw[dd * 4]);
                float a = cb[dd] + w4.w * bf2f((ushort)r3[j])
                        + w4.z * bf2f((ushort)r2[j])
                        + w4.y * bf2f((ushort)r1[j])
                        + w4.x * bf2f((ushort)r0[j]);
                o[j] = (short)f2bf(silu_f(a));
            }
            *(short8*)(u + (size_t)(bm + row) * DI + gcol) = o;
            int off = row * 128 + grp * 16;
            off ^= ((off >> 7) & 7) << 4;
            *(short8*)(smem + off) = o;
        }
#pragma unroll
        for (int i = 0; i < 2; i++) {   // W-tile: 64 rows x 128B
            int lin = (i * 256 + tid) * 16;
            int q = lin ^ (((lin >> 7) & 7) << 4);
            g2lds16(W + (size_t)(q >> 7) * K + k0 + ((q & 127) >> 1),
                    smem + BM * 128 + lin);
        }
        __syncthreads();
        const int rl = l & 15;
        const int kb0 = ((l >> 4) << 3) * 2;
#pragma unroll
        for (int kk = 0; kk < 2; kk++) {
            short8 af;
            {
                int off = (wr * 16 + rl) * 128 + kk * 64 + kb0;
                off ^= ((off >> 7) & 7) << 4;
                af = *(const short8*)(smem + off);
            }
            short8 bfr[2];
#pragma unroll
            for (int n = 0; n < 2; n++) {
                int off = (wc * 32 + n * 16 + rl) * 128 + kk * 64 + kb0;
                off ^= ((off >> 7) & 7) << 4;
                bfr[n] = *(const short8*)(smem + BM * 128 + off);
            }
#pragma unroll
            for (int n = 0; n < 2; n++)
                acc[n] = __builtin_amdgcn_mfma_f32_16x16x32_bf16(af, bfr[n], acc[n], 0, 0, 0);
        }
        __syncthreads();
    }
    const int row0 = bm + wr * 16 + ((l >> 4) << 2);
    const int col0 = wc * 32 + (l & 15);
#pragma unroll
    for (int n = 0; n < 2; n++) {
        int col = col0 + n * 16;
#pragma unroll
        for (int r = 0; r < 4; r++)
            Cf[(size_t)(row0 + r) * 64 + col] = acc[n][r];
    }
}

// ---- fused out_proj GEMM + residual + LayerNorm (BM=16, grid 512) ----
__global__ __launch_bounds__(256) void outproj_ln_kernel(
        const ushort* __restrict__ A,        // ygate [MR][512] bf16
        const ushort* __restrict__ W,        // opw_b [256][512] bf16
        const float* __restrict__ bias,      // opb [256]
        float* __restrict__ hres,            // residual stream f32 [MR][256]
        const float* __restrict__ lnw, const float* __restrict__ lnb,
        ushort* __restrict__ hln) {
    constexpr int K = DI;
    __shared__ __align__(16) char smem[(16 + 256) * 128];
    const int tid = threadIdx.x;
    const int l = tid & 63, w = tid >> 6;   // w = col-quarter
    const int bm = blockIdx.x * 16;

    f32x4 acc[4] = {};

    for (int k0 = 0; k0 < K; k0 += 64) {
        if (tid < 128) {   // A tile: 16 rows x 128B
            int lin = tid * 16;
            int q = lin ^ (((lin >> 7) & 7) << 4);
            g2lds16(A + (size_t)(bm + (q >> 7)) * K + k0 + ((q & 127) >> 1), smem + lin);
        }
#pragma unroll
        for (int i = 0; i < 8; i++) {   // W tile: 256 rows
            int lin = (i * 256 + tid) * 16;
            int q = lin ^ (((lin >> 7) & 7) << 4);
            g2lds16(W + (size_t)(q >> 7) * K + k0 + ((q & 127) >> 1), smem + 16 * 128 + lin);
        }
        __syncthreads();
        const int rl = l & 15;
        const int kb0 = ((l >> 4) << 3) * 2;
#pragma unroll
        for (int kk = 0; kk < 2; kk++) {
            short8 af;
            {
                int off = rl * 128 + kk * 64 + kb0;
                off ^= ((off >> 7) & 7) << 4;
                af = *(const short8*)(smem + off);
            }
            short8 bfr[4];
#pragma unroll
            for (int n = 0; n < 4; n++) {
                int off = (w * 64 + n * 16 + rl) * 128 + kk * 64 + kb0;
                off ^= ((off >> 7) & 7) << 4;
                bfr[n] = *(const short8*)(smem + 16 * 128 + off);
            }
#pragma unroll
            for (int n = 0; n < 4; n++)
                acc[n] = __builtin_amdgcn_mfma_f32_16x16x32_bf16(af, bfr[n], acc[n], 0, 0, 0);
        }
        __syncthreads();
    }

    const int r0 = (l >> 4) << 2;          // 0,4,8,12
    const int col0 = w * 64 + (l & 15);
    float vv[4][4];
    float s[4], q[4];
#pragma unroll
    for (int r = 0; r < 4; r++) { s[r] = 0.f; q[r] = 0.f; }
#pragma unroll
    for (int n = 0; n < 4; n++) {
        int col = col0 + n * 16;
        float bv = bias[col];
#pragma unroll
        for (int r = 0; r < 4; r++) {
            int row = bm + r0 + r;
            float x = acc[n][r] + bv + hres[(size_t)row * DM + col];
            vv[n][r] = x;
            s[r] += x;
            q[r] += x * x;
        }
    }
#pragma unroll
    for (int o = 1; o < 16; o <<= 1) {
#pragma unroll
        for (int r = 0; r < 4; r++) {
            s[r] += __shfl_xor(s[r], o);
            q[r] += __shfl_xor(q[r], o);
        }
    }
    float* red  = (float*)smem;            // [16][4]
    float* redq = red + 64;                // [16][4]
    if ((l & 15) == 0) {
#pragma unroll
        for (int r = 0; r < 4; r++) {
            int rl2 = r0 + r;
            red[rl2 * 4 + w] = s[r];
            redq[rl2 * 4 + w] = q[r];
        }
    }
    __syncthreads();
    float mu[4], rs[4];
#pragma unroll
    for (int r = 0; r < 4; r++) {
        int rl2 = r0 + r;
        float ts = red[rl2 * 4] + red[rl2 * 4 + 1] + red[rl2 * 4 + 2] + red[rl2 * 4 + 3];
        float tq = redq[rl2 * 4] + redq[rl2 * 4 + 1] + redq[rl2 * 4 + 2] + redq[rl2 * 4 + 3];
        mu[r] = ts * (1.0f / DM);
        float var = tq * (1.0f / DM) - mu[r] * mu[r];
        rs[r] = rsqrtf(var + 1e-5f);
    }
#pragma unroll
    for (int n = 0; n < 4; n++) {
        int col = col0 + n * 16;
        float lw = lnw[col], lb = lnb[col];
#pragma unroll
        for (int r = 0; r < 4; r++) {
            int row = bm + r0 + r;
            hres[(size_t)row * DM + col] = vv[n][r];
            hln[(size_t)row * DM + col] = f2bf((vv[n][r] - mu[r]) * rs[r] * lw + lb);
        }
    }
}

// ---- chunked parallel scan, algebraic split ----
// Phase 1: chunk-local pass. Outputs: S, sdv, packed (cumd,yloc) bf16x2.
__global__ __launch_bounds__(256, 4) void scan_phase1_kernel(
        const ushort* __restrict__ u, const float* __restrict__ x_dbl,
        const float* __restrict__ Av,
        const float* __restrict__ dtw, const float* __restrict__ dtb,
        const float* __restrict__ Dp,
        float* __restrict__ sdv, float* __restrict__ Sbuf,
        unsigned* __restrict__ cy) {
    __shared__ __align__(16) float xs[CLEN * 64];
    const int tid = threadIdx.x;
    const int bc = blockIdx.x >> 1;
    const int d = ((blockIdx.x & 1) << 8) + tid;
    const int c = bc & (NCHUNK - 1);
    const int b = bc >> 6;
    const int m0 = b * LL + c * CLEN;
    *reinterpret_cast<float4*>(&xs[tid * 4]) =
        *reinterpret_cast<const float4*>(&x_dbl[(size_t)m0 * 64 + tid * 4]);

    float Aval[DS], h[DS], wreg[DR];
#pragma unroll
    for (int q = 0; q < 4; q++) {
        float4 a4 = *reinterpret_cast<const float4*>(&Av[d * DS + q * 4]);
        Aval[q*4+0] = a4.x; Aval[q*4+1] = a4.y; Aval[q*4+2] = a4.z; Aval[q*4+3] = a4.w;
        float4 w4 = *reinterpret_cast<const float4*>(&dtw[d * DR + q * 4]);
        wreg[q*4] = w4.x; wreg[q*4+1] = w4.y; wreg[q*4+2] = w4.z; wreg[q*4+3] = w4.w;
    }
    float dbv = dtb[d];
    float Dval = Dp[d];
#pragma unroll
    for (int n = 0; n < DS; n++) h[n] = 0.f;
    const ushort* up = u + (size_t)m0 * DI + d;
    unsigned* cyp = cy + (size_t)m0 * DI + d;
    float sd = 0.f;
    __syncthreads();
    float uv = bf2f(up[0]);
    for (int t = 0; t < CLEN; t++) {
        float uvn = (t + 1 < CLEN) ? bf2f(up[(size_t)(t + 1) * DI]) : 0.f;
        const float* xr = &xs[t * 64];
        float4 x0 = *reinterpret_cast<const float4*>(xr);
        float4 x1 = *reinterpret_cast<const float4*>(xr + 4);
        float4 x2 = *reinterpret_cast<const float4*>(xr + 8);
        float4 x3 = *reinterpret_cast<const float4*>(xr + 12);
        float4 B0 = *reinterpret_cast<const float4*>(xr + 16);
        float4 B1 = *reinterpret_cast<const float4*>(xr + 20);
        float4 B2 = *reinterpret_cast<const float4*>(xr + 24);
        float4 B3 = *reinterpret_cast<const float4*>(xr + 28);
        float4 C0 = *reinterpret_cast<const float4*>(xr + 32);
        float4 C1 = *reinterpret_cast<const float4*>(xr + 36);
        float4 C2 = *reinterpret_cast<const float4*>(xr + 40);
        float4 C3 = *reinterpret_cast<const float4*>(xr + 44);
        float p0 = dbv + wreg[0]*x0.x + wreg[1]*x0.y + wreg[2]*x0.z + wreg[3]*x0.w;
        float p1 = wreg[4]*x1.x + wreg[5]*x1.y + wreg[6]*x1.z + wreg[7]*x1.w;
        float p2 = wreg[8]*x2.x + wreg[9]*x2.y + wreg[10]*x2.z + wreg[11]*x2.w;
        float p3 = wreg[12]*x3.x + wreg[13]*x3.y + wreg[14]*x3.z + wreg[15]*x3.w;
        float z = (p0 + p1) + (p2 + p3);
        float dv = (z > 20.0f) ? z : __logf(1.0f + __expf(z));
        sd += dv;
        float du = dv * uv;
        float a0, a1, a2, a3;
        h[0]  = exp2_f(dv*Aval[0])  * h[0]  + du * B0.x;  a0  = h[0]  * C0.x;
        h[1]  = exp2_f(dv*Aval[1])  * h[1]  + du * B0.y;  a0 += h[1]  * C0.y;
        h[2]  = exp2_f(dv*Aval[2])  * h[2]  + du * B0.z;  a0 += h[2]  * C0.z;
        h[3]  = exp2_f(dv*Aval[3])  * h[3]  + du * B0.w;  a0 += h[3]  * C0.w;
        h[4]  = exp2_f(dv*Aval[4])  * h[4]  + du * B1.x;  a1  = h[4]  * C1.x;
        h[5]  = exp2_f(dv*Aval[5])  * h[5]  + du * B1.y;  a1 += h[5]  * C1.y;
        h[6]  = exp2_f(dv*Aval[6])  * h[6]  + du * B1.z;  a1 += h[6]  * C1.z;
        h[7]  = exp2_f(dv*Aval[7])  * h[7]  + du * B1.w;  a1 += h[7]  * C1.w;
        h[8]  = exp2_f(dv*Aval[8])  * h[8]  + du * B2.x;  a2  = h[8]  * C2.x;
        h[9]  = exp2_f(dv*Aval[9])  * h[9]  + du * B2.y;  a2 += h[9]  * C2.y;
        h[10] = exp2_f(dv*Aval[10]) * h[10] + du * B2.z;  a2 += h[10] * C2.z;
        h[11] = exp2_f(dv*Aval[11]) * h[11] + du * B2.w;  a2 += h[11] * C2.w;
        h[12] = exp2_f(dv*Aval[12]) * h[12] + du * B3.x;  a3  = h[12] * C3.x;
        h[13] = exp2_f(dv*Aval[13]) * h[13] + du * B3.y;  a3 += h[13] * C3.y;
        h[14] = exp2_f(dv*Aval[14]) * h[14] + du * B3.z;  a3 += h[14] * C3.z;
        h[15] = exp2_f(dv*Aval[15]) * h[15] + du * B3.w;  a3 += h[15] * C3.w;
        float yv = ((a0 + a1) + (a2 + a3)) + Dval * uv;
        cyp[(size_t)t * DI] = (unsigned)f2bf(sd) | ((unsigned)f2bf(yv) << 16);
        uv = uvn;
    }
    size_t base = ((size_t)((b * NCHUNK + c) * DI + d)) * DS;
#pragma unroll
    for (int q = 0; q < 4; q++)
        *reinterpret_cast<float4*>(&Sbuf[base + q * 4]) =
            make_float4(h[q*4], h[q*4+1], h[q*4+2], h[q*4+3]);
    sdv[(b * NCHUNK + c) * DI + d] = sd;
}

// Phase 2: per (b,d,n) thread; batch-8 deep prefetch pipeline.
__global__ __launch_bounds__(256) void scan_phase2_kernel(
        const float* __restrict__ sdv, const float* __restrict__ Av,
        float* __restrict__ Sbuf) {
    int gid = blockIdx.x * 256 + threadIdx.x;
    int dn = gid & (DI * DS - 1);
    int b = gid >> 13;
    int n = dn & 15, d = dn >> 4;
    float Aval = Av[d * DS + n];
    size_t idx0 = (size_t)b * NCHUNK * DI * DS + dn;
    const size_t stride = (size_t)DI * DS;
    int sb0 = b * NCHUNK * DI + d;
    float h = 0.f;
    float S0[8], sd0[8];
#pragma unroll
    for (int j = 0; j < 8; j++) {
        S0[j] = Sbuf[idx0 + (size_t)j * stride];
        sd0[j] = sdv[sb0 + j * DI];
    }
    for (int g = 0; g < NCHUNK / 8; g++) {
        float S1[8], sd1[8];
        if (g < NCHUNK / 8 - 1) {
            int c1 = g * 8 + 8;
#pragma unroll
            for (int j = 0; j < 8; j++) {
                S1[j] = Sbuf[idx0 + (size_t)(c1 + j) * stride];
                sd1[j] = sdv[sb0 + (c1 + j) * DI];
            }
        } else {
#pragma unroll
            for (int j = 0; j < 8; j++) { S1[j] = 0.f; sd1[j] = 0.f; }
        }
#pragma unroll
        for (int j = 0; j < 8; j++) {
            float P = exp2_f(Aval * sd0[j]);
            Sbuf[idx0 + (size_t)(g * 8 + j) * stride] = h;
            h = P * h + S0[j];
        }
#pragma unroll
        for (int j = 0; j < 8; j++) { S0[j] = S1[j]; sd0[j] = sd1[j]; }
    }
}

// Phase 3 lite: y = (yloc + sum_n C[n]*exp2(Aval[n]*cumd)*hinit[n]) * silu(res)
__global__ __launch_bounds__(256, 4) void scan_phase3_kernel(
        const unsigned* __restrict__ cy,
        const float* __restrict__ x_dbl, const float* __restrict__ Av,
        const float* __restrict__ Sbuf,
        const ushort* __restrict__ xz, ushort* __restrict__ y) {
    __shared__ __align__(16) float cs[CLEN * 16];   // C slab only, 1 KB
    const int tid = threadIdx.x;
    const int bc = blockIdx.x >> 1;
    const int d = ((blockIdx.x & 1) << 8) + tid;
    const int c = bc & (NCHUNK - 1);
    const int b = bc >> 6;
    const int m0 = b * LL + c * CLEN;
    {   // stage C columns (32..47) of chunk rows
        int tt = tid >> 4, k = tid & 15;
        cs[tt * 16 + k] = x_dbl[(size_t)(m0 + tt) * 64 + 32 + k];
    }
    float Aval[DS], hi[DS];
    size_t base = ((size_t)((b * NCHUNK + c) * DI + d)) * DS;
#pragma unroll
    for (int q = 0; q < 4; q++) {
        float4 a4 = *reinterpret_cast<const float4*>(&Av[d * DS + q * 4]);
        Aval[q*4+0] = a4.x; Aval[q*4+1] = a4.y; Aval[q*4+2] = a4.z; Aval[q*4+3] = a4.w;
        float4 h4 = *reinterpret_cast<const float4*>(&Sbuf[base + q * 4]);
        hi[q*4] = h4.x; hi[q*4+1] = h4.y; hi[q*4+2] = h4.z; hi[q*4+3] = h4.w;
    }
    const unsigned* cyp = cy + (size_t)m0 * DI + d;
    const ushort* rp = xz + (size_t)m0 * 1024 + 512 + d;
    ushort* yp = y + (size_t)m0 * DI + d;
    __syncthreads();
    unsigned cyw = cyp[0];
    float rv = bf2f(rp[0]);
#pragma unroll 4
    for (int t = 0; t < CLEN; t++) {
        unsigned cywn = 0; float rvn = 0.f;
        if (t + 1 < CLEN) {
            cywn = cyp[(size_t)(t + 1) * DI];
            rvn = bf2f(rp[(size_t)(t + 1) * 1024]);
        }
        float cd = bf2f((ushort)(cyw & 0xffffu));
        float yl = bf2f((ushort)(cyw >> 16));
        const float* cr = &cs[t * 16];
        float4 C0 = *reinterpret_cast<const float4*>(cr);
        float4 C1 = *reinterpret_cast<const float4*>(cr + 4);
        float4 C2 = *reinterpret_cast<const float4*>(cr + 8);
        float4 C3 = *reinterpret_cast<const float4*>(cr + 12);
        float a0, a1, a2, a3;
        a0  = exp2_f(Aval[0]  * cd) * hi[0]  * C0.x;
        a0 += exp2_f(Aval[1]  * cd) * hi[1]  * C0.y;
        a0 += exp2_f(Aval[2]  * cd) * hi[2]  * C0.z;
        a0 += exp2_f(Aval[3]  * cd) * hi[3]  * C0.w;
        a1  = exp2_f(Aval[4]  * cd) * hi[4]  * C1.x;
        a1 += exp2_f(Aval[5]  * cd) * hi[5]  * C1.y;
        a1 += exp2_f(Aval[6]  * cd) * hi[6]  * C1.z;
        a1 += exp2_f(Aval[7]  * cd) * hi[7]  * C1.w;
        a2  = exp2_f(Aval[8]  * cd) * hi[8]  * C2.x;
        a2 += exp2_f(Aval[9]  * cd) * hi[9]  * C2.y;
        a2 += exp2_f(Aval[10] * cd) * hi[10] * C2.z;
        a2 += exp2_f(Aval[11] * cd) * hi[11] * C2.w;
        a3  = exp2_f(Aval[12] * cd) * hi[12] * C3.x;
        a3 += exp2_f(Aval[13] * cd) * hi[13] * C3.y;
        a3 += exp2_f(Aval[14] * cd) * hi[14] * C3.z;
        a3 += exp2_f(Aval[15] * cd) * hi[15] * C3.w;
        float yv = yl + ((a0 + a1) + (a2 + a3));
        yp[(size_t)t * DI] = f2bf(yv * silu_f(rv));
        cyw = cywn; rv = rvn;
    }
}

// pool stage 1: partial[(b*8+slice)][dm] = sum over 128 l's
__global__ __launch_bounds__(256) void pool_partial_kernel(const ushort* __restrict__ ln,
                                                           float* __restrict__ partial) {
    int bs = blockIdx.x;            // 0..63
    int b = bs >> 3, sl = bs & 7;
    int t = threadIdx.x;            // dm
    int l0 = sl * 128;
    float s = 0.f;
    for (int l = 0; l < 128; l++) s += bf2f(ln[(size_t)(b * LL + l0 + l) * DM + t]);
    partial[(bs << 8) + t] = s;
}

__global__ void cls_kernel(const float* __restrict__ partial, const float* __restrict__ cw,
                           const float* __restrict__ cb, float* __restrict__ out) {
    int t = threadIdx.x;
    if (t >= NB * NC) return;
    int b = t / NC, c = t % NC;
    float s = 0.f;
    for (int k = 0; k < DM; k++) {
        float p = 0.f;
#pragma unroll
        for (int sl = 0; sl < 8; sl++) p += partial[((b * 8 + sl) << 8) + k];
        s += p * cw[c * DM + k];
    }
    out[t] = cb[c] + s * (1.0f / LL);
}

extern "C" void kernel_launch(void* const* d_in, const int* in_sizes, int n_in,
                              void* d_out, int out_size, void* d_ws, size_t ws_size,
                              hipStream_t stream) {
    const float* x       = (const float*)d_in[0];
    const float* input_w = (const float*)d_in[1];
    const float* input_b = (const float*)d_in[2];
    const float* ln_w    = (const float*)d_in[3];
    const float* ln_b    = (const float*)d_in[4];
    const float* ipw     = (const float*)d_in[5];
    const float* ipb     = (const float*)d_in[6];
    const float* cw      = (const float*)d_in[7];
    const float* cb      = (const float*)d_in[8];
    const float* xpw     = (const float*)d_in[9];
    const float* dtw     = (const float*)d_in[10];
    const float* dtb     = (const float*)d_in[11];
    const float* A_log   = (const float*)d_in[12];
    const float* Dp      = (const float*)d_in[13];
    const float* opw     = (const float*)d_in[14];
    const float* opb     = (const float*)d_in[15];
    const float* norm_w  = (const float*)d_in[16];
    const float* norm_b  = (const float*)d_in[17];
    const float* cls_w   = (const float*)d_in[18];
    const float* cls_b   = (const float*)d_in[19];
    float* out = (float*)d_out;
    float* ws = (float*)d_ws;

    float*    hres   = ws;                                   // MR*DM f32
    ushort*   xz     = (ushort*)(hres + (size_t)MR * DM);    // MR*1024 bf16
    ushort*   ub     = xz + (size_t)MR * 1024;               // MR*DI bf16
    float*    x_dbl  = (float*)(ub + (size_t)MR * DI);       // MR*64 f32
    float*    sdvb   = x_dbl + (size_t)MR * 64;              // NB*NCHUNK*DI f32
    float*    Sbuf   = sdvb + (size_t)NB * NCHUNK * DI;      // NB*NCHUNK*DI*DS f32
    float*    partial= Sbuf + (size_t)NB * NCHUNK * DI * DS; // 64*256 f32
    ushort*   ygate  = (ushort*)(partial + 64 * 256);        // MR*DI bf16
    ushort*   hln    = ygate + (size_t)MR * DI;              // MR*DM bf16
    ushort*   ipw_b  = hln + (size_t)MR * DM;                // IPW_N
    ushort*   xpw_b  = ipw_b + IPW_N;                        // XPW_N
    ushort*   opw_b  = xpw_b + XPW_N;                        // OPW_N
    float*    Avbuf  = (float*)(opw_b + OPW_N);              // AV_N f32
    unsigned* cy     = (unsigned*)(Avbuf + AV_N);            // MR*DI packed bf16x2

    convert_weights_kernel<<<(IPW_N + XPW_N + OPW_N + AV_N) / 256, 256, 0, stream>>>(
        ipw, xpw, opw, A_log, ipw_b, xpw_b, opw_b, Avbuf);
    input_ln_kernel<<<MR, 256, 0, stream>>>(x, input_w, input_b, ln_w, ln_b, hres, hln);

    for (int i = 0; i < NL; i++) {
        mfma_gemm_kernel<128, 128, 2, 2, 0><<<dim3(MR / 128, 1024 / 128), 256, 0, stream>>>(
            hln, DM, ipw_b + (size_t)i * 2 * DI * DM, ipb + (size_t)i * 2 * DI,
            xz, nullptr, 1024, DM);
        xproj_conv_kernel<<<MR / 32, 256, 0, stream>>>(
            xz, cw + i * DI * DC, cb + i * DI, xpw_b + (size_t)i * 64 * DI, ub, x_dbl);
        scan_phase1_kernel<<<NB * NCHUNK * 2, 256, 0, stream>>>(
            ub, x_dbl, Avbuf + (size_t)i * DI * DS, dtw + i * DI * DR, dtb + i * DI,
            Dp + i * DI, sdvb, Sbuf, cy);
        scan_phase2_kernel<<<NB * DI * DS / 256, 256, 0, stream>>>(
            sdvb, Avbuf + (size_t)i * DI * DS, Sbuf);
        scan_phase3_kernel<<<NB * NCHUNK * 2, 256, 0, stream>>>(
            cy, x_dbl, Avbuf + (size_t)i * DI * DS, Sbuf, xz, ygate);
        const float* nlw = (i < NL - 1) ? (ln_w + (i + 1) * DM) : norm_w;
        const float* nlb = (i < NL - 1) ? (ln_b + (i + 1) * DM) : norm_b;
        outproj_ln_kernel<<<MR / 16, 256, 0, stream>>>(
            ygate, opw_b + (size_t)i * DM * DI, opb + (size_t)i * DM,
            hres, nlw, nlb, hln);
    }

    pool_partial_kernel<<<64, 256, 0, stream>>>(hln, partial);
    cls_kernel<<<1, 128, 0, stream>>>(partial, cls_w, cls_b, out);
}